// Round 11
// baseline (540.916 us; speedup 1.0000x reference)
//
#include <hip/hip_runtime.h>
#include <hip/hip_bf16.h>
#include <math.h>

#define HWX 4096
#define CCH 256
#define NB  4

typedef __attribute__((ext_vector_type(8))) short short8;
typedef __attribute__((ext_vector_type(4))) short short4v;
typedef __attribute__((ext_vector_type(4))) float f32x4;
typedef __attribute__((ext_vector_type(2))) float f32x2;

// ws layout (bytes)
#define WS_QT 0ull
#define WS_KT 8388608ull
#define WS_V  16777216ull
#define WS_W  25165824ull
#define WS_FT 25427968ull
#define WS_PO 33816576ull
// bf16 partial-O per split: 8388608 B ; bf16 partial-l per split: 32768 B
// pl base = WS_PO + S*8388608 ; need(S) = WS_PO + S*(8388608+32768)

__device__ __forceinline__ short f2bf(float f) {
  union { float f; unsigned u; } a; a.f = f;
  unsigned r = a.u + 0x7FFFu + ((a.u >> 16) & 1u);
  return (short)(r >> 16);
}

__device__ __forceinline__ float bf2f(short s) {
  union { unsigned u; float f; } a;
  a.u = ((unsigned)(unsigned short)s) << 16;
  return a.f;
}

__device__ __forceinline__ f32x4 mfma16(short8 a, short8 b, f32x4 c) {
  return __builtin_amdgcn_mfma_f32_16x16x32_bf16(a, b, c, 0, 0, 0);
}

__device__ __forceinline__ void gload16(const void* g, void* l) {
  __builtin_amdgcn_global_load_lds(
      (const __attribute__((address_space(1))) unsigned int*)g,
      (__attribute__((address_space(3))) unsigned int*)l, 16, 0, 0);
}

// K-image row permutation: image row a holds K row jmap(a);
// jmap(t*16 + 4g + r) = 8g + 4t + r.  invmap(j) = ((j>>2)&1)*16 + (j>>3)*4 + (j&3).
__device__ __forceinline__ int kt_invmap(int j) {
  return (((j >> 2) & 1) << 4) | (((j >> 3) & 3) << 2) | (j & 3);
}

// ---------------------------------------------------------------------------
// prep_qkv: one block per (b, 32-col tile). Produces bf16 swizzled images:
//   V  tile [256 c][32 j]: elem (c,j) at c*64 + j*2   ^ ((c&7)<<4)
//   KT tile [32 rows][256 c]: IMAGE ROW a holds K row jmap(a);
//          elem at a*512 + c*2 ^ ((a&7)<<4)
//   QT tile [32 i][256 c]: linear rows (row i = query i), same elem layout
// ---------------------------------------------------------------------------
__global__ __launch_bounds__(256) void prep_qkv(const float* __restrict__ pre,
                                                const float* __restrict__ cur,
                                                char* __restrict__ ws) {
  __shared__ short ldsT[256 * 36];
  const int tid = threadIdx.x;
  const int b  = blockIdx.x >> 7;
  const int jt = blockIdx.x & 127;
  const int j0 = jt * 32;
  const float* preB = pre + (size_t)b * CCH * HWX + j0;
  const float* curB = cur + (size_t)b * CCH * HWX + j0;
  char* vout = ws + WS_V  + (size_t)(b * 128 + jt) * 16384;
  char* kout = ws + WS_KT + (size_t)(b * 128 + jt) * 16384;
  char* qout = ws + WS_QT + (size_t)(b * 128 + jt) * 16384;

  short v[32];
  {
    const float* p = curB + (size_t)tid * HWX;
#pragma unroll
    for (int k = 0; k < 8; ++k) {
      f32x4 f = *(const f32x4*)(p + k * 4);
      v[k*4+0] = f2bf(f[0]); v[k*4+1] = f2bf(f[1]);
      v[k*4+2] = f2bf(f[2]); v[k*4+3] = f2bf(f[3]);
    }
  }
  // V image (row = c = tid), linear j order
#pragma unroll
  for (int k = 0; k < 4; ++k) {
    short8 o8;
#pragma unroll
    for (int e = 0; e < 8; ++e) o8[e] = v[k * 8 + e];
    *(short8*)(vout + ((tid * 64 + k * 16) ^ ((tid & 7) << 4))) = o8;
  }
  // KT image via LDS transpose; rows written PERMUTED (a = invmap(j))
#pragma unroll
  for (int j = 0; j < 32; ++j) ldsT[tid * 36 + j] = v[j];
  __syncthreads();
  {
    const int j = tid >> 3, m = tid & 7;
    const int a = kt_invmap(j);
#pragma unroll
    for (int k = 0; k < 4; ++k) {
      short8 o8;
#pragma unroll
      for (int e = 0; e < 8; ++e) o8[e] = ldsT[(m * 32 + k * 8 + e) * 36 + j];
      *(short8*)(kout + ((a * 512 + m * 64 + k * 16) ^ ((a & 7) << 4))) = o8;
    }
  }
  __syncthreads();
  // QT image (linear rows, from pre)
  {
    const float* p = preB + (size_t)tid * HWX;
#pragma unroll
    for (int k = 0; k < 8; ++k) {
      f32x4 f = *(const f32x4*)(p + k * 4);
      v[k*4+0] = f2bf(f[0]); v[k*4+1] = f2bf(f[1]);
      v[k*4+2] = f2bf(f[2]); v[k*4+3] = f2bf(f[3]);
    }
  }
#pragma unroll
  for (int j = 0; j < 32; ++j) ldsT[tid * 36 + j] = v[j];
  __syncthreads();
  {
    const int j = tid >> 3, m = tid & 7;
#pragma unroll
    for (int k = 0; k < 4; ++k) {
      short8 o8;
#pragma unroll
      for (int e = 0; e < 8; ++e) o8[e] = ldsT[(m * 32 + k * 8 + e) * 36 + j];
      *(short8*)(qout + ((j * 512 + m * 64 + k * 16) ^ ((j & 7) << 4))) = o8;
    }
  }
}

// ---------------------------------------------------------------------------
// prep_w: 8 blocks (one per 64-c K-slice). Slice image [256 o][64 c]:
//   elem (o,c) at o*128 + c*2 ^ ((o&7)<<4)
// ---------------------------------------------------------------------------
__global__ __launch_bounds__(256) void prep_w(const float* __restrict__ Wm,
                                              char* __restrict__ ws) {
  const int sl = blockIdx.x;
  const int o  = threadIdx.x;
  char* out = ws + WS_W + (size_t)sl * 32768;
  const float* src = Wm + (size_t)o * 512 + sl * 64;
  short tmp[64];
#pragma unroll
  for (int k = 0; k < 16; ++k) {
    f32x4 f = *(const f32x4*)(src + k * 4);
    tmp[k*4+0] = f2bf(f[0]); tmp[k*4+1] = f2bf(f[1]);
    tmp[k*4+2] = f2bf(f[2]); tmp[k*4+3] = f2bf(f[3]);
  }
#pragma unroll
  for (int k = 0; k < 8; ++k) {
    short8 o8;
#pragma unroll
    for (int e = 0; e < 8; ++e) o8[e] = tmp[k * 8 + e];
    *(short8*)(out + ((o * 128 + k * 16) ^ ((o & 7) << 4))) = o8;
  }
}

// ---------------------------------------------------------------------------
// attn_3blk: r9 math/layout EXACTLY, LDS cut 64->48KB for 3 blocks/CU:
//   - Q fragments read directly from global image (one-time, r7-validated)
//   - K double-buffered (32KB), V SINGLE-buffered (16KB)
//   - per iter: issue V(t),K(t+1) -> QK(t)+exp2 -> barrier A (drain) ->
//     PV(t) -> barrier B (sync-only, vmcnt already 0)
// Hazards: V(t) overwrite safe (all waves passed B(t-1) after PV(t-1));
// kbuf^1 overwrite safe (all waves passed A(t-1) after QK(t-1)).
// 256 thr, 3 blocks/CU = 12 waves/CU. S=4 split. Swapped QK^T, P in regs.
// ---------------------------------------------------------------------------
__global__ __launch_bounds__(256, 3) void attn_3blk(char* __restrict__ ws) {
  __shared__ __align__(16) char smem[49152];
  // kbuf0: 0..16K ; kbuf1: 16K..32K ; vbuf: 32K..48K
  const int tid = threadIdx.x, lane = tid & 63, wv = tid >> 6;
  const int g = lane >> 4, l15 = lane & 15;
  const int p = blockIdx.x;
  const int L = (p & 7) * 64 + (p >> 3);
  const int b = L >> 7, s = (L >> 5) & 3, it = L & 31;
  const int i0 = it * 128;
  const int NT = 32;
  const char* qimg  = ws + WS_QT + (size_t)(b * 128 + it * 4) * 16384;
  const char* kbase = ws + WS_KT + (size_t)(b * 128 + s * NT) * 16384;
  const char* vbase = ws + WS_V  + (size_t)(b * 128 + s * NT) * 16384;

  // ---- Q fragments straight from the global image (one-time) ----
  short8 qf[2][8];
  {
    const char* qw = qimg + (size_t)wv * 16384;
#pragma unroll
    for (int qsub = 0; qsub < 2; ++qsub)
#pragma unroll
      for (int kb = 0; kb < 8; ++kb)
        qf[qsub][kb] = *(const short8*)(qw + (qsub * 16 + l15) * 512 +
                                        ((kb * 64 + g * 16) ^ ((l15 & 7) << 4)));
  }

  f32x4 acc[2][16];
#pragma unroll
  for (int qsub = 0; qsub < 2; ++qsub)
#pragma unroll
    for (int nt = 0; nt < 16; ++nt) acc[qsub][nt] = (f32x4){0.f, 0.f, 0.f, 0.f};
  f32x4 accl[2];
  accl[0] = (f32x4){0.f, 0.f, 0.f, 0.f};
  accl[1] = (f32x4){0.f, 0.f, 0.f, 0.f};
  const float SL2E = 1.4426950408889634f / 16.0f;
  short8 ones;
#pragma unroll
  for (int e = 0; e < 8; ++e) ones[e] = (short)16256;  // bf16 1.0

  // prologue: stage K(0) into kbuf0
#pragma unroll
  for (int k = 0; k < 4; ++k)
    gload16(kbase + k * 4096 + tid * 16, smem + k * 4096 + tid * 16);
  __syncthreads();  // drains K(0)

  int cur = 0;
  for (int t = 0; t < NT; ++t) {
    // issue V(t) into vbuf (PV(t-1) complete for all waves via barrier B)
    {
      const char* vs = vbase + (size_t)t * 16384;
#pragma unroll
      for (int k = 0; k < 4; ++k)
        gload16(vs + k * 4096 + tid * 16, smem + 32768 + k * 4096 + tid * 16);
    }
    // issue K(t+1) into kbuf^1 (QK(t-1) readers done via barrier A(t-1))
    if (t + 1 < NT) {
      const char* ks = kbase + (size_t)(t + 1) * 16384;
      char* dst = smem + (cur ^ 1) * 16384 + tid * 16;
#pragma unroll
      for (int k = 0; k < 4; ++k)
        gload16(ks + k * 4096 + tid * 16, dst + k * 4096);
    }
    const char* bk = smem + cur * 16384;
    // S^T = K Q^T (swapped): A = K image rows (permuted), B = Q.
    f32x4 s00 = (f32x4){0.f,0.f,0.f,0.f}, s01 = (f32x4){0.f,0.f,0.f,0.f};
    f32x4 s10 = (f32x4){0.f,0.f,0.f,0.f}, s11 = (f32x4){0.f,0.f,0.f,0.f};
    __builtin_amdgcn_s_setprio(1);
#pragma unroll
    for (int kb = 0; kb < 8; ++kb) {
      const int co = (kb * 64 + g * 16) ^ ((l15 & 7) << 4);
      short8 k0 = *(const short8*)(bk + l15 * 512 + co);
      short8 k1 = *(const short8*)(bk + (l15 + 16) * 512 + co);
      s00 = mfma16(k0, qf[0][kb], s00);
      s01 = mfma16(k1, qf[0][kb], s01);
      s10 = mfma16(k0, qf[1][kb], s10);
      s11 = mfma16(k1, qf[1][kb], s11);
    }
    __builtin_amdgcn_s_setprio(0);
    // P = exp2(s/16*log2e - 16), static max; pack IN REGISTERS (PV A-frag).
    short8 pf0, pf1;
#pragma unroll
    for (int r = 0; r < 4; ++r) {
      pf0[r]     = f2bf(exp2f(fmaf(s00[r], SL2E, -16.0f)));
      pf0[4 + r] = f2bf(exp2f(fmaf(s01[r], SL2E, -16.0f)));
      pf1[r]     = f2bf(exp2f(fmaf(s10[r], SL2E, -16.0f)));
      pf1[4 + r] = f2bf(exp2f(fmaf(s11[r], SL2E, -16.0f)));
    }
    __syncthreads();  // barrier A: drains V(t) + K(t+1); syncs QK readers
    __builtin_amdgcn_s_setprio(1);
    accl[0] = mfma16(pf0, ones, accl[0]);  // row-sums, free in accumulator
    accl[1] = mfma16(pf1, ones, accl[1]);
    const char* bv = smem + 32768;
#pragma unroll
    for (int nt = 0; nt < 16; ++nt) {
      const int c = nt * 16 + l15;
      short8 vf = *(const short8*)(bv + ((c * 64 + g * 16) ^ ((c & 7) << 4)));
      acc[0][nt] = mfma16(pf0, vf, acc[0][nt]);
      acc[1][nt] = mfma16(pf1, vf, acc[1][nt]);
    }
    __builtin_amdgcn_s_setprio(0);
    __syncthreads();  // barrier B: PV readers done (vmcnt already 0 -> cheap)
    cur ^= 1;
  }

  // epilogue: write bf16 partial O and l (layouts unchanged from r9)
  short* po = (short*)(ws + WS_PO) + (size_t)(s * NB + b) * CCH * HWX;
#pragma unroll
  for (int qsub = 0; qsub < 2; ++qsub)
#pragma unroll
    for (int nt = 0; nt < 16; ++nt) {
      const int c = nt * 16 + l15;
      short4v o4;
#pragma unroll
      for (int r = 0; r < 4; ++r) o4[r] = f2bf(acc[qsub][nt][r]);
      *(short4v*)(po + (size_t)c * HWX + i0 + wv * 32 + qsub * 16 + g * 4) = o4;
    }
  if (l15 == 0) {
    short* pl = (short*)(ws + WS_PO + 4ull * 8388608ull) +
                (size_t)(s * NB + b) * HWX + i0 + wv * 32 + g * 4;
    short4v a4, b4;
#pragma unroll
    for (int r = 0; r < 4; ++r) { a4[r] = f2bf(accl[0][r]); b4[r] = f2bf(accl[1][r]); }
    *(short4v*)pl = a4;
    *(short4v*)(pl + 16) = b4;
  }
}

// ---------------------------------------------------------------------------
// attn_sb<S>: single-buffer fallback tiers (S=1,2), swapped scheme (r9).
// 128 thr / 2 waves, 64 q/block, LDS 32KB.
// ---------------------------------------------------------------------------
template <int S>
__global__ __launch_bounds__(128, 2) void attn_sb(char* __restrict__ ws) {
  __shared__ __align__(16) char smem[32768];
  const int tid = threadIdx.x, lane = tid & 63, wv = tid >> 6;
  const int g = lane >> 4, l15 = lane & 15;
  const int p = blockIdx.x;
  const int NT = 128 / S;
  int b, s, it;
  if (S == 2) {
    const int L = (p & 7) * 64 + (p >> 3);
    b = L >> 7; s = (L >> 6) & 1; it = L & 63;
  } else {
    const int L = (p & 7) * 32 + (p >> 3);
    b = L >> 6; s = 0; it = L & 63;
  }
  const int i0 = it * 64;
  const char* qimg  = ws + WS_QT + (size_t)(b * 128 + it * 2) * 16384;
  const char* kbase = ws + WS_KT + (size_t)(b * 128 + s * NT) * 16384;
  const char* vbase = ws + WS_V  + (size_t)(b * 128 + s * NT) * 16384;

  short8 qf[2][8];
  {
    const char* qw = qimg + (size_t)wv * 16384;
#pragma unroll
    for (int qsub = 0; qsub < 2; ++qsub)
#pragma unroll
      for (int kb = 0; kb < 8; ++kb)
        qf[qsub][kb] = *(const short8*)(qw + (qsub * 16 + l15) * 512 +
                                        ((kb * 64 + g * 16) ^ ((l15 & 7) << 4)));
  }

  f32x4 acc[2][16];
#pragma unroll
  for (int qsub = 0; qsub < 2; ++qsub)
#pragma unroll
    for (int nt = 0; nt < 16; ++nt) acc[qsub][nt] = (f32x4){0.f, 0.f, 0.f, 0.f};
  f32x4 accl[2];
  accl[0] = (f32x4){0.f, 0.f, 0.f, 0.f};
  accl[1] = (f32x4){0.f, 0.f, 0.f, 0.f};
  const float SL2E = 1.4426950408889634f / 16.0f;
  short8 ones;
#pragma unroll
  for (int e = 0; e < 8; ++e) ones[e] = (short)16256;

#pragma unroll
  for (int k = 0; k < 8; ++k) {
    gload16(kbase + k * 2048 + tid * 16, smem + k * 2048 + tid * 16);
    gload16(vbase + k * 2048 + tid * 16, smem + 16384 + k * 2048 + tid * 16);
  }
  __syncthreads();

  for (int t = 0; t < NT; ++t) {
    const char* bk = smem;
    const char* bv = smem + 16384;
    f32x4 s00 = (f32x4){0.f,0.f,0.f,0.f}, s01 = (f32x4){0.f,0.f,0.f,0.f};
    f32x4 s10 = (f32x4){0.f,0.f,0.f,0.f}, s11 = (f32x4){0.f,0.f,0.f,0.f};
    __builtin_amdgcn_s_setprio(1);
#pragma unroll
    for (int kb = 0; kb < 8; ++kb) {
      const int co = (kb * 64 + g * 16) ^ ((l15 & 7) << 4);
      short8 k0 = *(const short8*)(bk + l15 * 512 + co);
      short8 k1 = *(const short8*)(bk + (l15 + 16) * 512 + co);
      s00 = mfma16(k0, qf[0][kb], s00);
      s01 = mfma16(k1, qf[0][kb], s01);
      s10 = mfma16(k0, qf[1][kb], s10);
      s11 = mfma16(k1, qf[1][kb], s11);
    }
    __builtin_amdgcn_s_setprio(0);
    short8 pf0, pf1;
#pragma unroll
    for (int r = 0; r < 4; ++r) {
      pf0[r]     = f2bf(exp2f(fmaf(s00[r], SL2E, -16.0f)));
      pf0[4 + r] = f2bf(exp2f(fmaf(s01[r], SL2E, -16.0f)));
      pf1[r]     = f2bf(exp2f(fmaf(s10[r], SL2E, -16.0f)));
      pf1[4 + r] = f2bf(exp2f(fmaf(s11[r], SL2E, -16.0f)));
    }
    __builtin_amdgcn_s_setprio(1);
    accl[0] = mfma16(pf0, ones, accl[0]);
    accl[1] = mfma16(pf1, ones, accl[1]);
#pragma unroll
    for (int nt = 0; nt < 16; ++nt) {
      const int c = nt * 16 + l15;
      short8 vf = *(const short8*)(bv + ((c * 64 + g * 16) ^ ((c & 7) << 4)));
      acc[0][nt] = mfma16(pf0, vf, acc[0][nt]);
      acc[1][nt] = mfma16(pf1, vf, acc[1][nt]);
    }
    __builtin_amdgcn_s_setprio(0);
    __syncthreads();
    if (t + 1 < NT) {
      const char* ks = kbase + (size_t)(t + 1) * 16384;
      const char* vs = vbase + (size_t)(t + 1) * 16384;
#pragma unroll
      for (int k = 0; k < 8; ++k) {
        gload16(ks + k * 2048 + tid * 16, smem + k * 2048 + tid * 16);
        gload16(vs + k * 2048 + tid * 16, smem + 16384 + k * 2048 + tid * 16);
      }
    }
    __syncthreads();
  }

  short* po = (short*)(ws + WS_PO) + (size_t)(s * NB + b) * CCH * HWX;
#pragma unroll
  for (int qsub = 0; qsub < 2; ++qsub)
#pragma unroll
    for (int nt = 0; nt < 16; ++nt) {
      const int c = nt * 16 + l15;
      short4v o4;
#pragma unroll
      for (int r = 0; r < 4; ++r) o4[r] = f2bf(acc[qsub][nt][r]);
      *(short4v*)(po + (size_t)c * HWX + i0 + wv * 32 + qsub * 16 + g * 4) = o4;
    }
  if (l15 == 0) {
    short* pl = (short*)(ws + WS_PO + (size_t)S * 8388608ull) +
                (size_t)(s * NB + b) * HWX + i0 + wv * 32 + g * 4;
    short4v a4, b4;
#pragma unroll
    for (int r = 0; r < 4; ++r) { a4[r] = f2bf(accl[0][r]); b4[r] = f2bf(accl[1][r]); }
    *(short4v*)pl = a4;
    *(short4v*)(pl + 16) = b4;
  }
}

// ---------------------------------------------------------------------------
// merge_feat<S>: sum bf16 partials, divide by summed l, write featT tile
// images (linear rows). grid = NB*128 (32-i tiles), 256 thr.
// ---------------------------------------------------------------------------
template <int S>
__global__ __launch_bounds__(256) void merge_feat(char* __restrict__ ws) {
  __shared__ float linv[32];
  __shared__ short ldsT[32 * 66];
  const int tid = threadIdx.x;
  const int p = blockIdx.x;
  const int L = (p & 7) * 64 + (p >> 3);
  const int b = L >> 7, it = L & 127, i0 = it * 32;
  const short* po = (const short*)(ws + WS_PO);
  const short* pl = (const short*)(ws + WS_PO + (size_t)S * 8388608ull);
  if (tid < 32) {
    float l = 0.0f;
#pragma unroll
    for (int s = 0; s < S; ++s)
      l += bf2f(pl[(size_t)(s * NB + b) * HWX + i0 + tid]);
    linv[tid] = 1.0f / l;
  }
  __syncthreads();
  char* fout = ws + WS_FT + (size_t)(b * 128 + it) * 16384;
#pragma unroll
  for (int ch = 0; ch < 4; ++ch) {
    const int c = ch * 64 + (tid >> 2);
    const int qo = (tid & 3) * 8;
    float a[8];
#pragma unroll
    for (int e = 0; e < 8; ++e) a[e] = 0.0f;
#pragma unroll
    for (int s = 0; s < S; ++s) {
      short8 v8 = *(const short8*)(po + (size_t)(s * NB + b) * CCH * HWX +
                                   (size_t)c * HWX + i0 + qo);
#pragma unroll
      for (int e = 0; e < 8; ++e) a[e] += bf2f(v8[e]);
    }
#pragma unroll
    for (int e = 0; e < 8; ++e)
      ldsT[(qo + e) * 66 + (tid >> 2)] = f2bf(a[e] * linv[qo + e]);
    __syncthreads();
    {
      const int i = tid >> 3, m = tid & 7;
      short8 o8;
#pragma unroll
      for (int e = 0; e < 8; ++e) o8[e] = ldsT[i * 66 + m * 8 + e];
      *(short8*)(fout + ((i * 512 + ch * 128 + m * 16) ^ ((i & 7) << 4))) = o8;
    }
    __syncthreads();
  }
}

// ---------------------------------------------------------------------------
// conv_mfma: y = PReLU(BN(W * [featT; curT] + b)).  grid = NB*128 (32-i tiles).
// Slices 0-3 read ft (linear rows); slices 4-7 read kt (PERMUTED rows) ->
// bx row index goes through kt_invmap (2-way LDS conflict = free).
// ---------------------------------------------------------------------------
__global__ __launch_bounds__(256) void conv_mfma(const float* __restrict__ bconv,
                                                 const float* __restrict__ gamma,
                                                 const float* __restrict__ beta,
                                                 const float* __restrict__ rmean,
                                                 const float* __restrict__ rvar,
                                                 const float* __restrict__ alpha,
                                                 char* __restrict__ ws,
                                                 float* __restrict__ out) {
  __shared__ __align__(16) char smem[73728];
  const int tid = threadIdx.x, lane = tid & 63, wv = tid >> 6;
  const int g = lane >> 4, l15 = lane & 15;
  const int p = blockIdx.x;
  const int L = (p & 7) * 64 + (p >> 3);
  const int b = L >> 7, it = L & 127, i0 = it * 32;
  const char* wimg = ws + WS_W;
  const char* ft = ws + WS_FT + (size_t)(b * 128 + it) * 16384;
  const char* kt = ws + WS_KT + (size_t)(b * 128 + it) * 16384;

  f32x4 acc[4][2];
#pragma unroll
  for (int ot = 0; ot < 4; ++ot)
#pragma unroll
    for (int itt = 0; itt < 2; ++itt) acc[ot][itt] = (f32x4){0.f, 0.f, 0.f, 0.f};

  const int xi = wv * 8 + (lane >> 3), xw = (lane & 7) * 16;

#pragma unroll
  for (int k = 0; k < 8; ++k)
    gload16(wimg + wv * 8192 + k * 1024 + lane * 16,
            smem + wv * 8192 + k * 1024 + lane * 16);
  gload16(ft + xi * 512 + xw, smem + 65536 + wv * 1024 + lane * 16);
  __syncthreads();

  int cur = 0;
  for (int st = 0; st < 8; ++st) {
    if (st < 7) {
      const int sn = st + 1;
      const char* img = (sn < 4) ? ft : kt;
      const int coff = (sn & 3) * 128;
#pragma unroll
      for (int k = 0; k < 8; ++k)
        gload16(wimg + (size_t)sn * 32768 + wv * 8192 + k * 1024 + lane * 16,
                smem + (cur ^ 1) * 32768 + wv * 8192 + k * 1024 + lane * 16);
      gload16(img + xi * 512 + coff + xw,
              smem + 65536 + (cur ^ 1) * 4096 + wv * 1024 + lane * 16);
    }
    const char* wb = smem + cur * 32768;
    const char* xb = smem + 65536 + cur * 4096;
    short8 bx[2][2];
#pragma unroll
    for (int itt = 0; itt < 2; ++itt) {
      const int i = itt * 16 + l15;
      const int ii = (st < 4) ? i : kt_invmap(i);
#pragma unroll
      for (int kb = 0; kb < 2; ++kb)
        bx[itt][kb] = *(const short8*)(xb + ii * 128 + ((kb * 64 + g * 16) ^ ((ii & 7) << 4)));
    }
#pragma unroll
    for (int ot = 0; ot < 4; ++ot) {
      const int o = wv * 64 + ot * 16 + l15;
#pragma unroll
      for (int kb = 0; kb < 2; ++kb) {
        short8 aw = *(const short8*)(wb + o * 128 + ((kb * 64 + g * 16) ^ ((o & 7) << 4)));
#pragma unroll
        for (int itt = 0; itt < 2; ++itt)
          acc[ot][itt] = mfma16(aw, bx[itt][kb], acc[ot][itt]);
      }
    }
    __syncthreads();
    cur ^= 1;
  }

  const float a0 = alpha[0];
  float* outB = out + (size_t)b * CCH * HWX;
#pragma unroll
  for (int ot = 0; ot < 4; ++ot)
#pragma unroll
    for (int r = 0; r < 4; ++r) {
      const int o = wv * 64 + ot * 16 + g * 4 + r;
      const float inv = gamma[o] * rsqrtf(rvar[o] + 1e-5f);
      const float add = beta[o] - rmean[o] * inv + bconv[o] * inv;
#pragma unroll
      for (int itt = 0; itt < 2; ++itt) {
        float v = acc[ot][itt][r] * inv + add;
        v = (v >= 0.0f) ? v : a0 * v;
        outB[(size_t)o * HWX + i0 + itt * 16 + l15] = v;
      }
    }
}

// ===========================================================================
// Legacy fallback (round-2, validated) for small ws_size
// ===========================================================================
__global__ __launch_bounds__(256) void legacy_attn(const float* __restrict__ pre,
                                                   const float* __restrict__ cur,
                                                   float* __restrict__ feat) {
  __shared__ __align__(16) char smem[43008];
  short* lds_q  = (short*)smem;
  short* lds_kT = (short*)smem;
  short* lds_v  = (short*)(smem + 16896);
  short* lds_p  = (short*)(smem + 37376);
  const int tid = threadIdx.x, lane = tid & 63, wv = tid >> 6;
  const int b = blockIdx.x >> 6, i0 = (blockIdx.x & 63) * 64;
  const float* preB = pre + (size_t)b * CCH * HWX;
  const float* curB = cur + (size_t)b * CCH * HWX;
  float* featB = feat + (size_t)b * CCH * HWX;
  {
    const int ib = (tid & 15) * 4, cbb = (tid >> 4) * 4;
#pragma unroll
    for (int p = 0; p < 4; ++p) {
      const int c = cbb + 64 * p;
      f32x4 f[4];
#pragma unroll
      for (int r = 0; r < 4; ++r)
        f[r] = *(const f32x4*)(preB + (size_t)(c + r) * HWX + i0 + ib);
#pragma unroll
      for (int e = 0; e < 4; ++e) {
        short4v s2;
        s2[0] = f2bf(f[0][e]); s2[1] = f2bf(f[1][e]);
        s2[2] = f2bf(f[2][e]); s2[3] = f2bf(f[3][e]);
        *(short4v*)(&lds_q[(ib + e) * 264 + c]) = s2;
      }
    }
  }
  __syncthreads();
  short8 qf[8];
  {
    const int r = wv * 16 + (lane & 15), ko = (lane >> 4) * 8;
#pragma unroll
    for (int kb = 0; kb < 8; ++kb)
      qf[kb] = *(const short8*)(&lds_q[r * 264 + kb * 32 + ko]);
  }
  f32x4 acc[16];
#pragma unroll
  for (int nt = 0; nt < 16; ++nt) acc[nt] = (f32x4){0.f, 0.f, 0.f, 0.f};
  float m_run[4], l_run[4];
#pragma unroll
  for (int r = 0; r < 4; ++r) { m_run[r] = -1e30f; l_run[r] = 0.0f; }
  const float SL2E = 1.4426950408889634f / 16.0f;
  for (int jt = 0; jt < 128; ++jt) {
    const int j0 = jt * 32;
    __syncthreads();
    {
      const int jb = (tid & 7) * 4, cbb = (tid >> 3) * 4;
#pragma unroll
      for (int p = 0; p < 2; ++p) {
        const int c = cbb + 128 * p;
        f32x4 f[4];
#pragma unroll
        for (int r = 0; r < 4; ++r)
          f[r] = *(const f32x4*)(curB + (size_t)(c + r) * HWX + j0 + jb);
#pragma unroll
        for (int r = 0; r < 4; ++r) {
          short4v s2;
          s2[0] = f2bf(f[r][0]); s2[1] = f2bf(f[r][1]);
          s2[2] = f2bf(f[r][2]); s2[3] = f2bf(f[r][3]);
          *(short4v*)(&lds_v[(c + r) * 40 + jb]) = s2;
        }
#pragma unroll
        for (int e = 0; e < 4; ++e) {
          short4v s2;
          s2[0] = f2bf(f[0][e]); s2[1] = f2bf(f[1][e]);
          s2[2] = f2bf(f[2][e]); s2[3] = f2bf(f[3][e]);
          *(short4v*)(&lds_kT[(jb + e) * 264 + c]) = s2;
        }
      }
    }
    __syncthreads();
    f32x4 s0 = (f32x4){0.f,0.f,0.f,0.f}, s1 = (f32x4){0.f,0.f,0.f,0.f};
    {
      const int jc = lane & 15, ko = (lane >> 4) * 8;
#pragma unroll
      for (int kb = 0; kb < 8; ++kb) {
        short8 k0 = *(const short8*)(&lds_kT[jc * 264 + kb * 32 + ko]);
        short8 k1 = *(const short8*)(&lds_kT[(jc + 16) * 264 + kb * 32 + ko]);
        s0 = mfma16(qf[kb], k0, s0);
        s1 = mfma16(qf[kb], k1, s1);
      }
    }
    float p0[4], p1[4], corr[4];
#pragma unroll
    for (int r = 0; r < 4; ++r) {
      float t = fmaxf(s0[r], s1[r]);
      t = fmaxf(t, __shfl_xor(t, 1)); t = fmaxf(t, __shfl_xor(t, 2));
      t = fmaxf(t, __shfl_xor(t, 4)); t = fmaxf(t, __shfl_xor(t, 8));
      const float mn = fmaxf(m_run[r], t * SL2E);
      corr[r] = exp2f(m_run[r] - mn);
      m_run[r] = mn;
      p0[r] = exp2f(s0[r] * SL2E - mn);
      p1[r] = exp2f(s1[r] * SL2E - mn);
      float rs = p0[r] + p1[r];
      rs += __shfl_xor(rs, 1); rs += __shfl_xor(rs, 2);
      rs += __shfl_xor(rs, 4); rs += __shfl_xor(rs, 8);
      l_run[r] = l_run[r] * corr[r] + rs;
    }
#pragma unroll
    for (int nt = 0; nt < 16; ++nt)
#pragma unroll
      for (int r = 0; r < 4; ++r) acc[nt][r] *= corr[r];
    {
      short* pw = lds_p + wv * 640;
      const int g2 = lane >> 4, jc = lane & 15;
#pragma unroll
      for (int r = 0; r < 4; ++r) {
        pw[(g2 * 4 + r) * 40 + jc]      = f2bf(p0[r]);
        pw[(g2 * 4 + r) * 40 + 16 + jc] = f2bf(p1[r]);
      }
    }
    {
      const int g2 = lane >> 4, rr = lane & 15;
      short8 pf = *(const short8*)(&lds_p[wv * 640 + rr * 40 + g2 * 8]);
#pragma unroll
      for (int nt = 0; nt < 16; ++nt) {
        short8 vf = *(const short8*)(&lds_v[(nt * 16 + rr) * 40 + g2 * 8]);
        acc[nt] = mfma16(pf, vf, acc[nt]);
      }
    }
  }
  {
    const int g2 = lane >> 4, jc = lane & 15;
    float rl[4];
#pragma unroll
    for (int r = 0; r < 4; ++r) rl[r] = 1.0f / l_run[r];
#pragma unroll
    for (int nt = 0; nt < 16; ++nt) {
      const int c = nt * 16 + jc;
#pragma unroll
      for (int r = 0; r < 4; ++r)
        featB[(size_t)c * HWX + i0 + wv * 16 + g2 * 4 + r] = acc[nt][r] * rl[r];
    }
  }
}

__global__ __launch_bounds__(256) void legacy_conv(const float* feat,
                                                   const float* __restrict__ cur,
                                                   const float* __restrict__ Wm,
                                                   const float* __restrict__ bconv,
                                                   const float* __restrict__ gamma,
                                                   const float* __restrict__ beta,
                                                   const float* __restrict__ rmean,
                                                   const float* __restrict__ rvar,
                                                   const float* __restrict__ alpha,
                                                   float* out) {
  __shared__ __align__(16) char smem[25600];
  short* lds_w = (short*)smem;
  short* lds_x = (short*)(smem + 20480);
  const int tid = threadIdx.x, lane = tid & 63, wv = tid >> 6;
  const int b = blockIdx.x >> 6, i0 = (blockIdx.x & 63) * 64;
  const float* featB = feat + (size_t)b * CCH * HWX;
  const float* curB  = cur  + (size_t)b * CCH * HWX;
  f32x4 acc[4][4];
#pragma unroll
  for (int ot = 0; ot < 4; ++ot)
#pragma unroll
    for (int it = 0; it < 4; ++it) acc[ot][it] = (f32x4){0.f, 0.f, 0.f, 0.f};
  for (int ks = 0; ks < 16; ++ks) {
    const int k0 = ks * 32;
    __syncthreads();
    {
      const int kq = (tid & 7) * 4, ob = tid >> 3;
#pragma unroll
      for (int p = 0; p < 8; ++p) {
        const int o = ob + 32 * p;
        f32x4 f = *(const f32x4*)(Wm + (size_t)o * 512 + k0 + kq);
        short4v s2;
        s2[0] = f2bf(f[0]); s2[1] = f2bf(f[1]); s2[2] = f2bf(f[2]); s2[3] = f2bf(f[3]);
        *(short4v*)(&lds_w[o * 40 + kq]) = s2;
      }
    }
    {
      const int i2 = (tid & 31) * 2, cc = ((tid >> 5) & 7) * 4;
      const float* basep = (k0 < 256) ? (featB + (size_t)(k0 + cc) * HWX)
                                      : (curB + (size_t)(k0 + cc - 256) * HWX);
      f32x2 f[4];
#pragma unroll
      for (int r = 0; r < 4; ++r)
        f[r] = *(const f32x2*)(basep + (size_t)r * HWX + i0 + i2);
#pragma unroll
      for (int e = 0; e < 2; ++e) {
        short4v s2;
        s2[0] = f2bf(f[0][e]); s2[1] = f2bf(f[1][e]);
        s2[2] = f2bf(f[2][e]); s2[3] = f2bf(f[3][e]);
        *(short4v*)(&lds_x[(i2 + e) * 40 + cc]) = s2;
      }
    }
    __syncthreads();
    {
      const int g = lane >> 4, rr = lane & 15;
      short8 af[4], bx[4];
#pragma unroll
      for (int ot = 0; ot < 4; ++ot)
        af[ot] = *(const short8*)(&lds_w[(wv * 64 + ot * 16 + rr) * 40 + g * 8]);
#pragma unroll
      for (int it = 0; it < 4; ++it)
        bx[it] = *(const short8*)(&lds_x[(it * 16 + rr) * 40 + g * 8]);
#pragma unroll
      for (int ot = 0; ot < 4; ++ot)
#pragma unroll
        for (int it = 0; it < 4; ++it)
          acc[ot][it] = mfma16(af[ot], bx[it], acc[ot][it]);
    }
  }
  const float a0 = alpha[0];
  const int g = lane >> 4, ic = lane & 15;
  float* outB = out + (size_t)b * CCH * HWX;
#pragma unroll
  for (int ot = 0; ot < 4; ++ot)
#pragma unroll
    for (int r = 0; r < 4; ++r) {
      const int o = wv * 64 + ot * 16 + g * 4 + r;
      const float inv = gamma[o] * rsqrtf(rvar[o] + 1e-5f);
      const float add = beta[o] - rmean[o] * inv + bconv[o] * inv;
#pragma unroll
      for (int it = 0; it < 4; ++it) {
        float v = acc[ot][it][r] * inv + add;
        v = (v >= 0.0f) ? v : a0 * v;
        outB[(size_t)o * HWX + i0 + it * 16 + ic] = v;
      }
    }
}

extern "C" void kernel_launch(void* const* d_in, const int* in_sizes, int n_in,
                              void* d_out, int out_size, void* d_ws, size_t ws_size,
                              hipStream_t stream) {
  (void)in_sizes; (void)n_in; (void)out_size;
  const float* pre   = (const float*)d_in[0];
  const float* cur   = (const float*)d_in[1];
  const float* Wm    = (const float*)d_in[2];
  const float* bconv = (const float*)d_in[3];
  const float* gamma = (const float*)d_in[4];
  const float* beta  = (const float*)d_in[5];
  const float* rmean = (const float*)d_in[6];
  const float* rvar  = (const float*)d_in[7];
  const float* alpha = (const float*)d_in[8];
  float* out = (float*)d_out;
  char* ws = (char*)d_ws;

  const size_t need4 = WS_PO + 4ull * (8388608ull + 32768ull);  // 67,502,080
  const size_t need2 = WS_PO + 2ull * (8388608ull + 32768ull);
  const size_t need1 = WS_PO + 1ull * (8388608ull + 32768ull);

  if (ws_size >= need1) {
    prep_qkv<<<dim3(512), dim3(256), 0, stream>>>(pre, cur, ws);
    prep_w<<<dim3(8), dim3(256), 0, stream>>>(Wm, ws);
    if (ws_size >= need4) {
      attn_3blk<<<dim3(512), dim3(256), 0, stream>>>(ws);
      merge_feat<4><<<dim3(512), dim3(256), 0, stream>>>(ws);
    } else if (ws_size >= need2) {
      attn_sb<2><<<dim3(512), dim3(128), 0, stream>>>(ws);
      merge_feat<2><<<dim3(512), dim3(256), 0, stream>>>(ws);
    } else {
      attn_sb<1><<<dim3(256), dim3(128), 0, stream>>>(ws);
      merge_feat<1><<<dim3(512), dim3(256), 0, stream>>>(ws);
    }
    conv_mfma<<<dim3(512), dim3(256), 0, stream>>>(bconv, gamma, beta, rmean,
                                                   rvar, alpha, ws, out);
  } else {
    legacy_attn<<<dim3(256), dim3(256), 0, stream>>>(pre, cur, out);
    legacy_conv<<<dim3(256), dim3(256), 0, stream>>>(out, cur, Wm, bconv, gamma,
                                                     beta, rmean, rvar, alpha, out);
  }
}

// Round 12
// 129.290 us; speedup vs baseline: 4.1837x; 4.1837x over previous
//
#include <hip/hip_runtime.h>
#include <hip/hip_bf16.h>
#include <math.h>

#define HWX 4096
#define CCH 256
#define NB  4

typedef __attribute__((ext_vector_type(8))) short short8;
typedef __attribute__((ext_vector_type(4))) short short4v;
typedef __attribute__((ext_vector_type(4))) float f32x4;
typedef __attribute__((ext_vector_type(2))) float f32x2;

// ws layout (bytes)
#define WS_QT 0ull
#define WS_KT 8388608ull
#define WS_V  16777216ull
#define WS_W  25165824ull
#define WS_FT 25427968ull
#define WS_PO 33816576ull
// bf16 partial-O per split: 8388608 B ; bf16 partial-l per split: 32768 B
// pl base = WS_PO + S*8388608 ; need(S) = WS_PO + S*(8388608+32768)

__device__ __forceinline__ short f2bf(float f) {
  union { float f; unsigned u; } a; a.f = f;
  unsigned r = a.u + 0x7FFFu + ((a.u >> 16) & 1u);
  return (short)(r >> 16);
}

__device__ __forceinline__ float bf2f(short s) {
  union { unsigned u; float f; } a;
  a.u = ((unsigned)(unsigned short)s) << 16;
  return a.f;
}

__device__ __forceinline__ f32x4 mfma16(short8 a, short8 b, f32x4 c) {
  return __builtin_amdgcn_mfma_f32_16x16x32_bf16(a, b, c, 0, 0, 0);
}

__device__ __forceinline__ void gload16(const void* g, void* l) {
  __builtin_amdgcn_global_load_lds(
      (const __attribute__((address_space(1))) unsigned int*)g,
      (__attribute__((address_space(3))) unsigned int*)l, 16, 0, 0);
}

// K-image row permutation: image row a holds K row jmap(a);
// jmap(t*16 + 4g + r) = 8g + 4t + r.  invmap(j) = ((j>>2)&1)*16 + (j>>3)*4 + (j&3).
__device__ __forceinline__ int kt_invmap(int j) {
  return (((j >> 2) & 1) << 4) | (((j >> 3) & 3) << 2) | (j & 3);
}

// ---------------------------------------------------------------------------
// prep_qkv: one block per (b, 32-col tile). Produces bf16 swizzled images:
//   V  tile [256 c][32 j]: elem (c,j) at c*64 + j*2   ^ ((c&7)<<4)
//   KT tile [32 rows][256 c]: IMAGE ROW a holds K row jmap(a);
//          elem at a*512 + c*2 ^ ((a&7)<<4)
//   QT tile [32 i][256 c]: linear rows (row i = query i), same elem layout
// ---------------------------------------------------------------------------
__global__ __launch_bounds__(256) void prep_qkv(const float* __restrict__ pre,
                                                const float* __restrict__ cur,
                                                char* __restrict__ ws) {
  __shared__ short ldsT[256 * 36];
  const int tid = threadIdx.x;
  const int b  = blockIdx.x >> 7;
  const int jt = blockIdx.x & 127;
  const int j0 = jt * 32;
  const float* preB = pre + (size_t)b * CCH * HWX + j0;
  const float* curB = cur + (size_t)b * CCH * HWX + j0;
  char* vout = ws + WS_V  + (size_t)(b * 128 + jt) * 16384;
  char* kout = ws + WS_KT + (size_t)(b * 128 + jt) * 16384;
  char* qout = ws + WS_QT + (size_t)(b * 128 + jt) * 16384;

  short v[32];
  {
    const float* p = curB + (size_t)tid * HWX;
#pragma unroll
    for (int k = 0; k < 8; ++k) {
      f32x4 f = *(const f32x4*)(p + k * 4);
      v[k*4+0] = f2bf(f[0]); v[k*4+1] = f2bf(f[1]);
      v[k*4+2] = f2bf(f[2]); v[k*4+3] = f2bf(f[3]);
    }
  }
  // V image (row = c = tid), linear j order
#pragma unroll
  for (int k = 0; k < 4; ++k) {
    short8 o8;
#pragma unroll
    for (int e = 0; e < 8; ++e) o8[e] = v[k * 8 + e];
    *(short8*)(vout + ((tid * 64 + k * 16) ^ ((tid & 7) << 4))) = o8;
  }
  // KT image via LDS transpose; rows written PERMUTED (a = invmap(j))
#pragma unroll
  for (int j = 0; j < 32; ++j) ldsT[tid * 36 + j] = v[j];
  __syncthreads();
  {
    const int j = tid >> 3, m = tid & 7;
    const int a = kt_invmap(j);
#pragma unroll
    for (int k = 0; k < 4; ++k) {
      short8 o8;
#pragma unroll
      for (int e = 0; e < 8; ++e) o8[e] = ldsT[(m * 32 + k * 8 + e) * 36 + j];
      *(short8*)(kout + ((a * 512 + m * 64 + k * 16) ^ ((a & 7) << 4))) = o8;
    }
  }
  __syncthreads();
  // QT image (linear rows, from pre)
  {
    const float* p = preB + (size_t)tid * HWX;
#pragma unroll
    for (int k = 0; k < 8; ++k) {
      f32x4 f = *(const f32x4*)(p + k * 4);
      v[k*4+0] = f2bf(f[0]); v[k*4+1] = f2bf(f[1]);
      v[k*4+2] = f2bf(f[2]); v[k*4+3] = f2bf(f[3]);
    }
  }
#pragma unroll
  for (int j = 0; j < 32; ++j) ldsT[tid * 36 + j] = v[j];
  __syncthreads();
  {
    const int j = tid >> 3, m = tid & 7;
#pragma unroll
    for (int k = 0; k < 4; ++k) {
      short8 o8;
#pragma unroll
      for (int e = 0; e < 8; ++e) o8[e] = ldsT[(m * 32 + k * 8 + e) * 36 + j];
      *(short8*)(qout + ((j * 512 + m * 64 + k * 16) ^ ((j & 7) << 4))) = o8;
    }
  }
}

// ---------------------------------------------------------------------------
// prep_w: 8 blocks (one per 64-c K-slice). Slice image [256 o][64 c]:
//   elem (o,c) at o*128 + c*2 ^ ((o&7)<<4)
// ---------------------------------------------------------------------------
__global__ __launch_bounds__(256) void prep_w(const float* __restrict__ Wm,
                                              char* __restrict__ ws) {
  const int sl = blockIdx.x;
  const int o  = threadIdx.x;
  char* out = ws + WS_W + (size_t)sl * 32768;
  const float* src = Wm + (size_t)o * 512 + sl * 64;
  short tmp[64];
#pragma unroll
  for (int k = 0; k < 16; ++k) {
    f32x4 f = *(const f32x4*)(src + k * 4);
    tmp[k*4+0] = f2bf(f[0]); tmp[k*4+1] = f2bf(f[1]);
    tmp[k*4+2] = f2bf(f[2]); tmp[k*4+3] = f2bf(f[3]);
  }
#pragma unroll
  for (int k = 0; k < 8; ++k) {
    short8 o8;
#pragma unroll
    for (int e = 0; e < 8; ++e) o8[e] = tmp[k * 8 + e];
    *(short8*)(out + ((o * 128 + k * 16) ^ ((o & 7) << 4))) = o8;
  }
}

// ---------------------------------------------------------------------------
// attn_db4: flash attention, S=4 split, double-buffered K/V in LDS +
// SWAPPED QK^T (S^T = mfma(K,Q)) with row-permuted K image: lane (g,i)
// ends holding P[i, 8g..8g+7] == the PV A-fragment; P never touches LDS.
// LDS 64KB, 256 thr, 2 blocks/CU (register-capped: ~230 regs/wave).
// Writes bf16 partial O [s][b][c][i] and bf16 partial l [s][b][i] to ws.
// ---------------------------------------------------------------------------
__global__ __launch_bounds__(256, 2) void attn_db4(char* __restrict__ ws) {
  __shared__ __align__(16) char smem[65536];
  // buf0: K 0..16384, V 16384..32768 ; buf1: 32768..65536
  const int tid = threadIdx.x, lane = tid & 63, wv = tid >> 6;
  const int g = lane >> 4, l15 = lane & 15;
  const int p = blockIdx.x;
  const int L = (p & 7) * 64 + (p >> 3);
  const int b = L >> 7, s = (L >> 5) & 3, it = L & 31;
  const int i0 = it * 128;
  const int NT = 32;
  const char* qimg  = ws + WS_QT + (size_t)(b * 128 + it * 4) * 16384;
  const char* kbase = ws + WS_KT + (size_t)(b * 128 + s * NT) * 16384;
  const char* vbase = ws + WS_V  + (size_t)(b * 128 + s * NT) * 16384;

  // ---- stage the block's 4 Q tiles (64KB), pull wave's 32 rows to regs ----
#pragma unroll
  for (int k = 0; k < 16; ++k)
    gload16(qimg + k * 4096 + tid * 16, smem + k * 4096 + tid * 16);
  __syncthreads();
  short8 qf[2][8];
  {
    const char* qt = smem + wv * 16384;
#pragma unroll
    for (int qsub = 0; qsub < 2; ++qsub)
#pragma unroll
      for (int kb = 0; kb < 8; ++kb)
        qf[qsub][kb] = *(const short8*)(qt + (qsub * 16 + l15) * 512 +
                                        ((kb * 64 + g * 16) ^ ((l15 & 7) << 4)));
  }
  __syncthreads();

  f32x4 acc[2][16];
#pragma unroll
  for (int qsub = 0; qsub < 2; ++qsub)
#pragma unroll
    for (int nt = 0; nt < 16; ++nt) acc[qsub][nt] = (f32x4){0.f, 0.f, 0.f, 0.f};
  f32x4 accl[2];
  accl[0] = (f32x4){0.f, 0.f, 0.f, 0.f};
  accl[1] = (f32x4){0.f, 0.f, 0.f, 0.f};
  const float SL2E = 1.4426950408889634f / 16.0f;
  short8 ones;
#pragma unroll
  for (int e = 0; e < 8; ++e) ones[e] = (short)16256;  // bf16 1.0

  // prologue: stage tile 0 into buf0 (K 16KB + V 16KB)
#pragma unroll
  for (int k = 0; k < 4; ++k) {
    gload16(kbase + k * 4096 + tid * 16, smem + k * 4096 + tid * 16);
    gload16(vbase + k * 4096 + tid * 16, smem + 16384 + k * 4096 + tid * 16);
  }
  __syncthreads();

  int cur = 0;
  for (int t = 0; t < NT; ++t) {
    // prefetch t+1 into buf^1 BEFORE compute
    if (t + 1 < NT) {
      const char* ks = kbase + (size_t)(t + 1) * 16384;
      const char* vs = vbase + (size_t)(t + 1) * 16384;
      char* dst = smem + (cur ^ 1) * 32768 + tid * 16;
#pragma unroll
      for (int k = 0; k < 4; ++k) {
        gload16(ks + k * 4096 + tid * 16, dst + k * 4096);
        gload16(vs + k * 4096 + tid * 16, dst + 16384 + k * 4096);
      }
    }
    const char* bk = smem + cur * 32768;
    const char* bv = bk + 16384;
    // S^T = K Q^T (swapped): A = K image rows (permuted), B = Q.
    f32x4 s00 = (f32x4){0.f,0.f,0.f,0.f}, s01 = (f32x4){0.f,0.f,0.f,0.f};
    f32x4 s10 = (f32x4){0.f,0.f,0.f,0.f}, s11 = (f32x4){0.f,0.f,0.f,0.f};
    __builtin_amdgcn_s_setprio(1);
#pragma unroll
    for (int kb = 0; kb < 8; ++kb) {
      const int co = (kb * 64 + g * 16) ^ ((l15 & 7) << 4);
      short8 k0 = *(const short8*)(bk + l15 * 512 + co);
      short8 k1 = *(const short8*)(bk + (l15 + 16) * 512 + co);
      s00 = mfma16(k0, qf[0][kb], s00);
      s01 = mfma16(k1, qf[0][kb], s01);
      s10 = mfma16(k0, qf[1][kb], s10);
      s11 = mfma16(k1, qf[1][kb], s11);
    }
    __builtin_amdgcn_s_setprio(0);
    // P = exp2(s/16*log2e - 16), static max; pack IN REGISTERS (PV A-frag).
    short8 pf0, pf1;
#pragma unroll
    for (int r = 0; r < 4; ++r) {
      pf0[r]     = f2bf(exp2f(fmaf(s00[r], SL2E, -16.0f)));
      pf0[4 + r] = f2bf(exp2f(fmaf(s01[r], SL2E, -16.0f)));
      pf1[r]     = f2bf(exp2f(fmaf(s10[r], SL2E, -16.0f)));
      pf1[4 + r] = f2bf(exp2f(fmaf(s11[r], SL2E, -16.0f)));
    }
    __builtin_amdgcn_s_setprio(1);
    accl[0] = mfma16(pf0, ones, accl[0]);  // row-sums, free in accumulator
    accl[1] = mfma16(pf1, ones, accl[1]);
#pragma unroll
    for (int nt = 0; nt < 16; ++nt) {
      const int c = nt * 16 + l15;
      short8 vf = *(const short8*)(bv + ((c * 64 + g * 16) ^ ((c & 7) << 4)));
      acc[0][nt] = mfma16(pf0, vf, acc[0][nt]);
      acc[1][nt] = mfma16(pf1, vf, acc[1][nt]);
    }
    __builtin_amdgcn_s_setprio(0);
    __syncthreads();  // drains prefetch + protects buf swap
    cur ^= 1;
  }

  // epilogue: write bf16 partial O and l
  short* po = (short*)(ws + WS_PO) + (size_t)(s * NB + b) * CCH * HWX;
#pragma unroll
  for (int qsub = 0; qsub < 2; ++qsub)
#pragma unroll
    for (int nt = 0; nt < 16; ++nt) {
      const int c = nt * 16 + l15;
      short4v o4;
#pragma unroll
      for (int r = 0; r < 4; ++r) o4[r] = f2bf(acc[qsub][nt][r]);
      *(short4v*)(po + (size_t)c * HWX + i0 + wv * 32 + qsub * 16 + g * 4) = o4;
    }
  if (l15 == 0) {
    short* pl = (short*)(ws + WS_PO + 4ull * 8388608ull) +
                (size_t)(s * NB + b) * HWX + i0 + wv * 32 + g * 4;
    short4v a4, b4;
#pragma unroll
    for (int r = 0; r < 4; ++r) { a4[r] = f2bf(accl[0][r]); b4[r] = f2bf(accl[1][r]); }
    *(short4v*)pl = a4;
    *(short4v*)(pl + 16) = b4;
  }
}

// ---------------------------------------------------------------------------
// attn_sb<S>: single-buffer fallback tiers (S=1,2), same swapped scheme.
// 128 thr / 2 waves, 64 q/block, LDS 32KB.
// ---------------------------------------------------------------------------
template <int S>
__global__ __launch_bounds__(128, 2) void attn_sb(char* __restrict__ ws) {
  __shared__ __align__(16) char smem[32768];
  const int tid = threadIdx.x, lane = tid & 63, wv = tid >> 6;
  const int g = lane >> 4, l15 = lane & 15;
  const int p = blockIdx.x;
  const int NT = 128 / S;
  int b, s, it;
  if (S == 2) {
    const int L = (p & 7) * 64 + (p >> 3);
    b = L >> 7; s = (L >> 6) & 1; it = L & 63;
  } else {
    const int L = (p & 7) * 32 + (p >> 3);
    b = L >> 6; s = 0; it = L & 63;
  }
  const int i0 = it * 64;
  const char* qimg  = ws + WS_QT + (size_t)(b * 128 + it * 2) * 16384;
  const char* kbase = ws + WS_KT + (size_t)(b * 128 + s * NT) * 16384;
  const char* vbase = ws + WS_V  + (size_t)(b * 128 + s * NT) * 16384;

#pragma unroll
  for (int k = 0; k < 16; ++k)
    gload16(qimg + k * 2048 + tid * 16, smem + k * 2048 + tid * 16);
  __syncthreads();
  short8 qf[2][8];
  {
    const char* qt = smem + wv * 16384;
#pragma unroll
    for (int qsub = 0; qsub < 2; ++qsub)
#pragma unroll
      for (int kb = 0; kb < 8; ++kb)
        qf[qsub][kb] = *(const short8*)(qt + (qsub * 16 + l15) * 512 +
                                        ((kb * 64 + g * 16) ^ ((l15 & 7) << 4)));
  }
  __syncthreads();

  f32x4 acc[2][16];
#pragma unroll
  for (int qsub = 0; qsub < 2; ++qsub)
#pragma unroll
    for (int nt = 0; nt < 16; ++nt) acc[qsub][nt] = (f32x4){0.f, 0.f, 0.f, 0.f};
  f32x4 accl[2];
  accl[0] = (f32x4){0.f, 0.f, 0.f, 0.f};
  accl[1] = (f32x4){0.f, 0.f, 0.f, 0.f};
  const float SL2E = 1.4426950408889634f / 16.0f;
  short8 ones;
#pragma unroll
  for (int e = 0; e < 8; ++e) ones[e] = (short)16256;

#pragma unroll
  for (int k = 0; k < 8; ++k) {
    gload16(kbase + k * 2048 + tid * 16, smem + k * 2048 + tid * 16);
    gload16(vbase + k * 2048 + tid * 16, smem + 16384 + k * 2048 + tid * 16);
  }
  __syncthreads();

  for (int t = 0; t < NT; ++t) {
    const char* bk = smem;
    const char* bv = smem + 16384;
    f32x4 s00 = (f32x4){0.f,0.f,0.f,0.f}, s01 = (f32x4){0.f,0.f,0.f,0.f};
    f32x4 s10 = (f32x4){0.f,0.f,0.f,0.f}, s11 = (f32x4){0.f,0.f,0.f,0.f};
    __builtin_amdgcn_s_setprio(1);
#pragma unroll
    for (int kb = 0; kb < 8; ++kb) {
      const int co = (kb * 64 + g * 16) ^ ((l15 & 7) << 4);
      short8 k0 = *(const short8*)(bk + l15 * 512 + co);
      short8 k1 = *(const short8*)(bk + (l15 + 16) * 512 + co);
      s00 = mfma16(k0, qf[0][kb], s00);
      s01 = mfma16(k1, qf[0][kb], s01);
      s10 = mfma16(k0, qf[1][kb], s10);
      s11 = mfma16(k1, qf[1][kb], s11);
    }
    __builtin_amdgcn_s_setprio(0);
    short8 pf0, pf1;
#pragma unroll
    for (int r = 0; r < 4; ++r) {
      pf0[r]     = f2bf(exp2f(fmaf(s00[r], SL2E, -16.0f)));
      pf0[4 + r] = f2bf(exp2f(fmaf(s01[r], SL2E, -16.0f)));
      pf1[r]     = f2bf(exp2f(fmaf(s10[r], SL2E, -16.0f)));
      pf1[4 + r] = f2bf(exp2f(fmaf(s11[r], SL2E, -16.0f)));
    }
    __builtin_amdgcn_s_setprio(1);
    accl[0] = mfma16(pf0, ones, accl[0]);
    accl[1] = mfma16(pf1, ones, accl[1]);
#pragma unroll
    for (int nt = 0; nt < 16; ++nt) {
      const int c = nt * 16 + l15;
      short8 vf = *(const short8*)(bv + ((c * 64 + g * 16) ^ ((c & 7) << 4)));
      acc[0][nt] = mfma16(pf0, vf, acc[0][nt]);
      acc[1][nt] = mfma16(pf1, vf, acc[1][nt]);
    }
    __builtin_amdgcn_s_setprio(0);
    __syncthreads();
    if (t + 1 < NT) {
      const char* ks = kbase + (size_t)(t + 1) * 16384;
      const char* vs = vbase + (size_t)(t + 1) * 16384;
#pragma unroll
      for (int k = 0; k < 8; ++k) {
        gload16(ks + k * 2048 + tid * 16, smem + k * 2048 + tid * 16);
        gload16(vs + k * 2048 + tid * 16, smem + 16384 + k * 2048 + tid * 16);
      }
    }
    __syncthreads();
  }

  short* po = (short*)(ws + WS_PO) + (size_t)(s * NB + b) * CCH * HWX;
#pragma unroll
  for (int qsub = 0; qsub < 2; ++qsub)
#pragma unroll
    for (int nt = 0; nt < 16; ++nt) {
      const int c = nt * 16 + l15;
      short4v o4;
#pragma unroll
      for (int r = 0; r < 4; ++r) o4[r] = f2bf(acc[qsub][nt][r]);
      *(short4v*)(po + (size_t)c * HWX + i0 + wv * 32 + qsub * 16 + g * 4) = o4;
    }
  if (l15 == 0) {
    short* pl = (short*)(ws + WS_PO + (size_t)S * 8388608ull) +
                (size_t)(s * NB + b) * HWX + i0 + wv * 32 + g * 4;
    short4v a4, b4;
#pragma unroll
    for (int r = 0; r < 4; ++r) { a4[r] = f2bf(accl[0][r]); b4[r] = f2bf(accl[1][r]); }
    *(short4v*)pl = a4;
    *(short4v*)(pl + 16) = b4;
  }
}

// ---------------------------------------------------------------------------
// merge_feat<S>: sum bf16 partials, divide by summed l, write featT tile
// images (linear rows). grid = NB*128 (32-i tiles), 256 thr.
// ---------------------------------------------------------------------------
template <int S>
__global__ __launch_bounds__(256) void merge_feat(char* __restrict__ ws) {
  __shared__ float linv[32];
  __shared__ short ldsT[32 * 66];
  const int tid = threadIdx.x;
  const int p = blockIdx.x;
  const int L = (p & 7) * 64 + (p >> 3);
  const int b = L >> 7, it = L & 127, i0 = it * 32;
  const short* po = (const short*)(ws + WS_PO);
  const short* pl = (const short*)(ws + WS_PO + (size_t)S * 8388608ull);
  if (tid < 32) {
    float l = 0.0f;
#pragma unroll
    for (int s = 0; s < S; ++s)
      l += bf2f(pl[(size_t)(s * NB + b) * HWX + i0 + tid]);
    linv[tid] = 1.0f / l;
  }
  __syncthreads();
  char* fout = ws + WS_FT + (size_t)(b * 128 + it) * 16384;
#pragma unroll
  for (int ch = 0; ch < 4; ++ch) {
    const int c = ch * 64 + (tid >> 2);
    const int qo = (tid & 3) * 8;
    float a[8];
#pragma unroll
    for (int e = 0; e < 8; ++e) a[e] = 0.0f;
#pragma unroll
    for (int s = 0; s < S; ++s) {
      short8 v8 = *(const short8*)(po + (size_t)(s * NB + b) * CCH * HWX +
                                   (size_t)c * HWX + i0 + qo);
#pragma unroll
      for (int e = 0; e < 8; ++e) a[e] += bf2f(v8[e]);
    }
#pragma unroll
    for (int e = 0; e < 8; ++e)
      ldsT[(qo + e) * 66 + (tid >> 2)] = f2bf(a[e] * linv[qo + e]);
    __syncthreads();
    {
      const int i = tid >> 3, m = tid & 7;
      short8 o8;
#pragma unroll
      for (int e = 0; e < 8; ++e) o8[e] = ldsT[i * 66 + m * 8 + e];
      *(short8*)(fout + ((i * 512 + ch * 128 + m * 16) ^ ((i & 7) << 4))) = o8;
    }
    __syncthreads();
  }
}

// ---------------------------------------------------------------------------
// conv_mfma: y = PReLU(BN(W * [featT; curT] + b)).  grid = NB*128 (32-i tiles).
// Slices 0-3 read ft (linear rows); slices 4-7 read kt (PERMUTED rows) ->
// bx row index goes through kt_invmap (2-way LDS conflict = free).
// ---------------------------------------------------------------------------
__global__ __launch_bounds__(256) void conv_mfma(const float* __restrict__ bconv,
                                                 const float* __restrict__ gamma,
                                                 const float* __restrict__ beta,
                                                 const float* __restrict__ rmean,
                                                 const float* __restrict__ rvar,
                                                 const float* __restrict__ alpha,
                                                 char* __restrict__ ws,
                                                 float* __restrict__ out) {
  __shared__ __align__(16) char smem[73728];
  const int tid = threadIdx.x, lane = tid & 63, wv = tid >> 6;
  const int g = lane >> 4, l15 = lane & 15;
  const int p = blockIdx.x;
  const int L = (p & 7) * 64 + (p >> 3);
  const int b = L >> 7, it = L & 127, i0 = it * 32;
  const char* wimg = ws + WS_W;
  const char* ft = ws + WS_FT + (size_t)(b * 128 + it) * 16384;
  const char* kt = ws + WS_KT + (size_t)(b * 128 + it) * 16384;

  f32x4 acc[4][2];
#pragma unroll
  for (int ot = 0; ot < 4; ++ot)
#pragma unroll
    for (int itt = 0; itt < 2; ++itt) acc[ot][itt] = (f32x4){0.f, 0.f, 0.f, 0.f};

  const int xi = wv * 8 + (lane >> 3), xw = (lane & 7) * 16;

#pragma unroll
  for (int k = 0; k < 8; ++k)
    gload16(wimg + wv * 8192 + k * 1024 + lane * 16,
            smem + wv * 8192 + k * 1024 + lane * 16);
  gload16(ft + xi * 512 + xw, smem + 65536 + wv * 1024 + lane * 16);
  __syncthreads();

  int cur = 0;
  for (int st = 0; st < 8; ++st) {
    if (st < 7) {
      const int sn = st + 1;
      const char* img = (sn < 4) ? ft : kt;
      const int coff = (sn & 3) * 128;
#pragma unroll
      for (int k = 0; k < 8; ++k)
        gload16(wimg + (size_t)sn * 32768 + wv * 8192 + k * 1024 + lane * 16,
                smem + (cur ^ 1) * 32768 + wv * 8192 + k * 1024 + lane * 16);
      gload16(img + xi * 512 + coff + xw,
              smem + 65536 + (cur ^ 1) * 4096 + wv * 1024 + lane * 16);
    }
    const char* wb = smem + cur * 32768;
    const char* xb = smem + 65536 + cur * 4096;
    short8 bx[2][2];
#pragma unroll
    for (int itt = 0; itt < 2; ++itt) {
      const int i = itt * 16 + l15;
      const int ii = (st < 4) ? i : kt_invmap(i);
#pragma unroll
      for (int kb = 0; kb < 2; ++kb)
        bx[itt][kb] = *(const short8*)(xb + ii * 128 + ((kb * 64 + g * 16) ^ ((ii & 7) << 4)));
    }
#pragma unroll
    for (int ot = 0; ot < 4; ++ot) {
      const int o = wv * 64 + ot * 16 + l15;
#pragma unroll
      for (int kb = 0; kb < 2; ++kb) {
        short8 aw = *(const short8*)(wb + o * 128 + ((kb * 64 + g * 16) ^ ((o & 7) << 4)));
#pragma unroll
        for (int itt = 0; itt < 2; ++itt)
          acc[ot][itt] = mfma16(aw, bx[itt][kb], acc[ot][itt]);
      }
    }
    __syncthreads();
    cur ^= 1;
  }

  const float a0 = alpha[0];
  float* outB = out + (size_t)b * CCH * HWX;
#pragma unroll
  for (int ot = 0; ot < 4; ++ot)
#pragma unroll
    for (int r = 0; r < 4; ++r) {
      const int o = wv * 64 + ot * 16 + g * 4 + r;
      const float inv = gamma[o] * rsqrtf(rvar[o] + 1e-5f);
      const float add = beta[o] - rmean[o] * inv + bconv[o] * inv;
#pragma unroll
      for (int itt = 0; itt < 2; ++itt) {
        float v = acc[ot][itt][r] * inv + add;
        v = (v >= 0.0f) ? v : a0 * v;
        outB[(size_t)o * HWX + i0 + itt * 16 + l15] = v;
      }
    }
}

// ===========================================================================
// Legacy fallback (round-2, validated) for small ws_size
// ===========================================================================
__global__ __launch_bounds__(256) void legacy_attn(const float* __restrict__ pre,
                                                   const float* __restrict__ cur,
                                                   float* __restrict__ feat) {
  __shared__ __align__(16) char smem[43008];
  short* lds_q  = (short*)smem;
  short* lds_kT = (short*)smem;
  short* lds_v  = (short*)(smem + 16896);
  short* lds_p  = (short*)(smem + 37376);
  const int tid = threadIdx.x, lane = tid & 63, wv = tid >> 6;
  const int b = blockIdx.x >> 6, i0 = (blockIdx.x & 63) * 64;
  const float* preB = pre + (size_t)b * CCH * HWX;
  const float* curB = cur + (size_t)b * CCH * HWX;
  float* featB = feat + (size_t)b * CCH * HWX;
  {
    const int ib = (tid & 15) * 4, cbb = (tid >> 4) * 4;
#pragma unroll
    for (int p = 0; p < 4; ++p) {
      const int c = cbb + 64 * p;
      f32x4 f[4];
#pragma unroll
      for (int r = 0; r < 4; ++r)
        f[r] = *(const f32x4*)(preB + (size_t)(c + r) * HWX + i0 + ib);
#pragma unroll
      for (int e = 0; e < 4; ++e) {
        short4v s2;
        s2[0] = f2bf(f[0][e]); s2[1] = f2bf(f[1][e]);
        s2[2] = f2bf(f[2][e]); s2[3] = f2bf(f[3][e]);
        *(short4v*)(&lds_q[(ib + e) * 264 + c]) = s2;
      }
    }
  }
  __syncthreads();
  short8 qf[8];
  {
    const int r = wv * 16 + (lane & 15), ko = (lane >> 4) * 8;
#pragma unroll
    for (int kb = 0; kb < 8; ++kb)
      qf[kb] = *(const short8*)(&lds_q[r * 264 + kb * 32 + ko]);
  }
  f32x4 acc[16];
#pragma unroll
  for (int nt = 0; nt < 16; ++nt) acc[nt] = (f32x4){0.f, 0.f, 0.f, 0.f};
  float m_run[4], l_run[4];
#pragma unroll
  for (int r = 0; r < 4; ++r) { m_run[r] = -1e30f; l_run[r] = 0.0f; }
  const float SL2E = 1.4426950408889634f / 16.0f;
  for (int jt = 0; jt < 128; ++jt) {
    const int j0 = jt * 32;
    __syncthreads();
    {
      const int jb = (tid & 7) * 4, cbb = (tid >> 3) * 4;
#pragma unroll
      for (int p = 0; p < 2; ++p) {
        const int c = cbb + 128 * p;
        f32x4 f[4];
#pragma unroll
        for (int r = 0; r < 4; ++r)
          f[r] = *(const f32x4*)(curB + (size_t)(c + r) * HWX + j0 + jb);
#pragma unroll
        for (int r = 0; r < 4; ++r) {
          short4v s2;
          s2[0] = f2bf(f[r][0]); s2[1] = f2bf(f[r][1]);
          s2[2] = f2bf(f[r][2]); s2[3] = f2bf(f[r][3]);
          *(short4v*)(&lds_v[(c + r) * 40 + jb]) = s2;
        }
#pragma unroll
        for (int e = 0; e < 4; ++e) {
          short4v s2;
          s2[0] = f2bf(f[0][e]); s2[1] = f2bf(f[1][e]);
          s2[2] = f2bf(f[2][e]); s2[3] = f2bf(f[3][e]);
          *(short4v*)(&lds_kT[(jb + e) * 264 + c]) = s2;
        }
      }
    }
    __syncthreads();
    f32x4 s0 = (f32x4){0.f,0.f,0.f,0.f}, s1 = (f32x4){0.f,0.f,0.f,0.f};
    {
      const int jc = lane & 15, ko = (lane >> 4) * 8;
#pragma unroll
      for (int kb = 0; kb < 8; ++kb) {
        short8 k0 = *(const short8*)(&lds_kT[jc * 264 + kb * 32 + ko]);
        short8 k1 = *(const short8*)(&lds_kT[(jc + 16) * 264 + kb * 32 + ko]);
        s0 = mfma16(qf[kb], k0, s0);
        s1 = mfma16(qf[kb], k1, s1);
      }
    }
    float p0[4], p1[4], corr[4];
#pragma unroll
    for (int r = 0; r < 4; ++r) {
      float t = fmaxf(s0[r], s1[r]);
      t = fmaxf(t, __shfl_xor(t, 1)); t = fmaxf(t, __shfl_xor(t, 2));
      t = fmaxf(t, __shfl_xor(t, 4)); t = fmaxf(t, __shfl_xor(t, 8));
      const float mn = fmaxf(m_run[r], t * SL2E);
      corr[r] = exp2f(m_run[r] - mn);
      m_run[r] = mn;
      p0[r] = exp2f(s0[r] * SL2E - mn);
      p1[r] = exp2f(s1[r] * SL2E - mn);
      float rs = p0[r] + p1[r];
      rs += __shfl_xor(rs, 1); rs += __shfl_xor(rs, 2);
      rs += __shfl_xor(rs, 4); rs += __shfl_xor(rs, 8);
      l_run[r] = l_run[r] * corr[r] + rs;
    }
#pragma unroll
    for (int nt = 0; nt < 16; ++nt)
#pragma unroll
      for (int r = 0; r < 4; ++r) acc[nt][r] *= corr[r];
    {
      short* pw = lds_p + wv * 640;
      const int g2 = lane >> 4, jc = lane & 15;
#pragma unroll
      for (int r = 0; r < 4; ++r) {
        pw[(g2 * 4 + r) * 40 + jc]      = f2bf(p0[r]);
        pw[(g2 * 4 + r) * 40 + 16 + jc] = f2bf(p1[r]);
      }
    }
    {
      const int g2 = lane >> 4, rr = lane & 15;
      short8 pf = *(const short8*)(&lds_p[wv * 640 + rr * 40 + g2 * 8]);
#pragma unroll
      for (int nt = 0; nt < 16; ++nt) {
        short8 vf = *(const short8*)(&lds_v[(nt * 16 + rr) * 40 + g2 * 8]);
        acc[nt] = mfma16(pf, vf, acc[nt]);
      }
    }
  }
  {
    const int g2 = lane >> 4, jc = lane & 15;
    float rl[4];
#pragma unroll
    for (int r = 0; r < 4; ++r) rl[r] = 1.0f / l_run[r];
#pragma unroll
    for (int nt = 0; nt < 16; ++nt) {
      const int c = nt * 16 + jc;
#pragma unroll
      for (int r = 0; r < 4; ++r)
        featB[(size_t)c * HWX + i0 + wv * 16 + g2 * 4 + r] = acc[nt][r] * rl[r];
    }
  }
}

__global__ __launch_bounds__(256) void legacy_conv(const float* feat,
                                                   const float* __restrict__ cur,
                                                   const float* __restrict__ Wm,
                                                   const float* __restrict__ bconv,
                                                   const float* __restrict__ gamma,
                                                   const float* __restrict__ beta,
                                                   const float* __restrict__ rmean,
                                                   const float* __restrict__ rvar,
                                                   const float* __restrict__ alpha,
                                                   float* out) {
  __shared__ __align__(16) char smem[25600];
  short* lds_w = (short*)smem;
  short* lds_x = (short*)(smem + 20480);
  const int tid = threadIdx.x, lane = tid & 63, wv = tid >> 6;
  const int b = blockIdx.x >> 6, i0 = (blockIdx.x & 63) * 64;
  const float* featB = feat + (size_t)b * CCH * HWX;
  const float* curB  = cur  + (size_t)b * CCH * HWX;
  f32x4 acc[4][4];
#pragma unroll
  for (int ot = 0; ot < 4; ++ot)
#pragma unroll
    for (int it = 0; it < 4; ++it) acc[ot][it] = (f32x4){0.f, 0.f, 0.f, 0.f};
  for (int ks = 0; ks < 16; ++ks) {
    const int k0 = ks * 32;
    __syncthreads();
    {
      const int kq = (tid & 7) * 4, ob = tid >> 3;
#pragma unroll
      for (int p = 0; p < 8; ++p) {
        const int o = ob + 32 * p;
        f32x4 f = *(const f32x4*)(Wm + (size_t)o * 512 + k0 + kq);
        short4v s2;
        s2[0] = f2bf(f[0]); s2[1] = f2bf(f[1]); s2[2] = f2bf(f[2]); s2[3] = f2bf(f[3]);
        *(short4v*)(&lds_w[o * 40 + kq]) = s2;
      }
    }
    {
      const int i2 = (tid & 31) * 2, cc = ((tid >> 5) & 7) * 4;
      const float* basep = (k0 < 256) ? (featB + (size_t)(k0 + cc) * HWX)
                                      : (curB + (size_t)(k0 + cc - 256) * HWX);
      f32x2 f[4];
#pragma unroll
      for (int r = 0; r < 4; ++r)
        f[r] = *(const f32x2*)(basep + (size_t)r * HWX + i0 + i2);
#pragma unroll
      for (int e = 0; e < 2; ++e) {
        short4v s2;
        s2[0] = f2bf(f[0][e]); s2[1] = f2bf(f[1][e]);
        s2[2] = f2bf(f[2][e]); s2[3] = f2bf(f[3][e]);
        *(short4v*)(&lds_x[(i2 + e) * 40 + cc]) = s2;
      }
    }
    __syncthreads();
    {
      const int g = lane >> 4, rr = lane & 15;
      short8 af[4], bx[4];
#pragma unroll
      for (int ot = 0; ot < 4; ++ot)
        af[ot] = *(const short8*)(&lds_w[(wv * 64 + ot * 16 + rr) * 40 + g * 8]);
#pragma unroll
      for (int it = 0; it < 4; ++it)
        bx[it] = *(const short8*)(&lds_x[(it * 16 + rr) * 40 + g * 8]);
#pragma unroll
      for (int ot = 0; ot < 4; ++ot)
#pragma unroll
        for (int it = 0; it < 4; ++it)
          acc[ot][it] = mfma16(af[ot], bx[it], acc[ot][it]);
    }
  }
  const float a0 = alpha[0];
  const int g = lane >> 4, ic = lane & 15;
  float* outB = out + (size_t)b * CCH * HWX;
#pragma unroll
  for (int ot = 0; ot < 4; ++ot)
#pragma unroll
    for (int r = 0; r < 4; ++r) {
      const int o = wv * 64 + ot * 16 + g * 4 + r;
      const float inv = gamma[o] * rsqrtf(rvar[o] + 1e-5f);
      const float add = beta[o] - rmean[o] * inv + bconv[o] * inv;
#pragma unroll
      for (int it = 0; it < 4; ++it) {
        float v = acc[ot][it][r] * inv + add;
        v = (v >= 0.0f) ? v : a0 * v;
        outB[(size_t)o * HWX + i0 + it * 16 + ic] = v;
      }
    }
}

extern "C" void kernel_launch(void* const* d_in, const int* in_sizes, int n_in,
                              void* d_out, int out_size, void* d_ws, size_t ws_size,
                              hipStream_t stream) {
  (void)in_sizes; (void)n_in; (void)out_size;
  const float* pre   = (const float*)d_in[0];
  const float* cur   = (const float*)d_in[1];
  const float* Wm    = (const float*)d_in[2];
  const float* bconv = (const float*)d_in[3];
  const float* gamma = (const float*)d_in[4];
  const float* beta  = (const float*)d_in[5];
  const float* rmean = (const float*)d_in[6];
  const float* rvar  = (const float*)d_in[7];
  const float* alpha = (const float*)d_in[8];
  float* out = (float*)d_out;
  char* ws = (char*)d_ws;

  const size_t need4 = WS_PO + 4ull * (8388608ull + 32768ull);  // 67,502,080
  const size_t need2 = WS_PO + 2ull * (8388608ull + 32768ull);
  const size_t need1 = WS_PO + 1ull * (8388608ull + 32768ull);

  if (ws_size >= need1) {
    prep_qkv<<<dim3(512), dim3(256), 0, stream>>>(pre, cur, ws);
    prep_w<<<dim3(8), dim3(256), 0, stream>>>(Wm, ws);
    if (ws_size >= need4) {
      attn_db4<<<dim3(512), dim3(256), 0, stream>>>(ws);
      merge_feat<4><<<dim3(512), dim3(256), 0, stream>>>(ws);
    } else if (ws_size >= need2) {
      attn_sb<2><<<dim3(512), dim3(128), 0, stream>>>(ws);
      merge_feat<2><<<dim3(512), dim3(256), 0, stream>>>(ws);
    } else {
      attn_sb<1><<<dim3(256), dim3(128), 0, stream>>>(ws);
      merge_feat<1><<<dim3(512), dim3(256), 0, stream>>>(ws);
    }
    conv_mfma<<<dim3(512), dim3(256), 0, stream>>>(bconv, gamma, beta, rmean,
                                                   rvar, alpha, ws, out);
  } else {
    legacy_attn<<<dim3(256), dim3(256), 0, stream>>>(pre, cur, out);
    legacy_conv<<<dim3(256), dim3(256), 0, stream>>>(out, cur, Wm, bconv, gamma,
                                                     beta, rmean, rvar, alpha, out);
  }
}

// Round 13
// 124.485 us; speedup vs baseline: 4.3452x; 1.0386x over previous
//
#include <hip/hip_runtime.h>
#include <hip/hip_bf16.h>
#include <math.h>

#define HWX 4096
#define CCH 256
#define NB  4

typedef __attribute__((ext_vector_type(8))) short short8;
typedef __attribute__((ext_vector_type(4))) short short4v;
typedef __attribute__((ext_vector_type(4))) float f32x4;
typedef __attribute__((ext_vector_type(2))) float f32x2;

// ws layout (bytes)
#define WS_QT 0ull
#define WS_KT 8388608ull
#define WS_V  16777216ull
#define WS_W  25165824ull
#define WS_FT 25427968ull
#define WS_PO 33816576ull
// bf16 partial-O per split: 8388608 B ; bf16 partial-l per split: 32768 B
// pl base = WS_PO + S*8388608 ; need(S) = WS_PO + S*(8388608+32768)

__device__ __forceinline__ short f2bf(float f) {
  union { float f; unsigned u; } a; a.f = f;
  unsigned r = a.u + 0x7FFFu + ((a.u >> 16) & 1u);
  return (short)(r >> 16);
}

__device__ __forceinline__ float bf2f(short s) {
  union { unsigned u; float f; } a;
  a.u = ((unsigned)(unsigned short)s) << 16;
  return a.f;
}

// hardware convert — measured 7us faster than manual 3-op RNE in attn hot loop
__device__ __forceinline__ short f2bf_rn(float f) {
  __hip_bfloat16 h = __float2bfloat16(f);
  return *reinterpret_cast<short*>(&h);
}

__device__ __forceinline__ f32x4 mfma16(short8 a, short8 b, f32x4 c) {
  return __builtin_amdgcn_mfma_f32_16x16x32_bf16(a, b, c, 0, 0, 0);
}

__device__ __forceinline__ void gload16(const void* g, void* l) {
  __builtin_amdgcn_global_load_lds(
      (const __attribute__((address_space(1))) unsigned int*)g,
      (__attribute__((address_space(3))) unsigned int*)l, 16, 0, 0);
}

// K-image row permutation: image row a holds K row jmap(a);
// jmap(t*16 + 4g + r) = 8g + 4t + r.  invmap(j) = ((j>>2)&1)*16 + (j>>3)*4 + (j&3).
__device__ __forceinline__ int kt_invmap(int j) {
  return (((j >> 2) & 1) << 4) | (((j >> 3) & 3) << 2) | (j & 3);
}

// ---------------------------------------------------------------------------
// prep_qkv: one block per (b, 32-col tile). Produces bf16 swizzled images:
//   V  tile [256 c][32 j]: elem (c,j) at c*64 + j*2   ^ ((c&7)<<4)
//   KT tile [32 rows][256 c]: IMAGE ROW a holds K row jmap(a);
//          elem at a*512 + c*2 ^ ((a&7)<<4)
//   QT tile [32 i][256 c]: linear rows (row i = query i), same elem layout
// ---------------------------------------------------------------------------
__global__ __launch_bounds__(256) void prep_qkv(const float* __restrict__ pre,
                                                const float* __restrict__ cur,
                                                char* __restrict__ ws) {
  __shared__ short ldsT[256 * 36];
  const int tid = threadIdx.x;
  const int b  = blockIdx.x >> 7;
  const int jt = blockIdx.x & 127;
  const int j0 = jt * 32;
  const float* preB = pre + (size_t)b * CCH * HWX + j0;
  const float* curB = cur + (size_t)b * CCH * HWX + j0;
  char* vout = ws + WS_V  + (size_t)(b * 128 + jt) * 16384;
  char* kout = ws + WS_KT + (size_t)(b * 128 + jt) * 16384;
  char* qout = ws + WS_QT + (size_t)(b * 128 + jt) * 16384;

  short v[32];
  {
    const float* p = curB + (size_t)tid * HWX;
#pragma unroll
    for (int k = 0; k < 8; ++k) {
      f32x4 f = *(const f32x4*)(p + k * 4);
      v[k*4+0] = f2bf(f[0]); v[k*4+1] = f2bf(f[1]);
      v[k*4+2] = f2bf(f[2]); v[k*4+3] = f2bf(f[3]);
    }
  }
  // V image (row = c = tid), linear j order
#pragma unroll
  for (int k = 0; k < 4; ++k) {
    short8 o8;
#pragma unroll
    for (int e = 0; e < 8; ++e) o8[e] = v[k * 8 + e];
    *(short8*)(vout + ((tid * 64 + k * 16) ^ ((tid & 7) << 4))) = o8;
  }
  // KT image via LDS transpose; rows written PERMUTED (a = invmap(j))
#pragma unroll
  for (int j = 0; j < 32; ++j) ldsT[tid * 36 + j] = v[j];
  __syncthreads();
  {
    const int j = tid >> 3, m = tid & 7;
    const int a = kt_invmap(j);
#pragma unroll
    for (int k = 0; k < 4; ++k) {
      short8 o8;
#pragma unroll
      for (int e = 0; e < 8; ++e) o8[e] = ldsT[(m * 32 + k * 8 + e) * 36 + j];
      *(short8*)(kout + ((a * 512 + m * 64 + k * 16) ^ ((a & 7) << 4))) = o8;
    }
  }
  __syncthreads();
  // QT image (linear rows, from pre)
  {
    const float* p = preB + (size_t)tid * HWX;
#pragma unroll
    for (int k = 0; k < 8; ++k) {
      f32x4 f = *(const f32x4*)(p + k * 4);
      v[k*4+0] = f2bf(f[0]); v[k*4+1] = f2bf(f[1]);
      v[k*4+2] = f2bf(f[2]); v[k*4+3] = f2bf(f[3]);
    }
  }
#pragma unroll
  for (int j = 0; j < 32; ++j) ldsT[tid * 36 + j] = v[j];
  __syncthreads();
  {
    const int j = tid >> 3, m = tid & 7;
#pragma unroll
    for (int k = 0; k < 4; ++k) {
      short8 o8;
#pragma unroll
      for (int e = 0; e < 8; ++e) o8[e] = ldsT[(m * 32 + k * 8 + e) * 36 + j];
      *(short8*)(qout + ((j * 512 + m * 64 + k * 16) ^ ((j & 7) << 4))) = o8;
    }
  }
}

// ---------------------------------------------------------------------------
// prep_w: 8 blocks (one per 64-c K-slice). Slice image [256 o][64 c]:
//   elem (o,c) at o*128 + c*2 ^ ((o&7)<<4)
// ---------------------------------------------------------------------------
__global__ __launch_bounds__(256) void prep_w(const float* __restrict__ Wm,
                                              char* __restrict__ ws) {
  const int sl = blockIdx.x;
  const int o  = threadIdx.x;
  char* out = ws + WS_W + (size_t)sl * 32768;
  const float* src = Wm + (size_t)o * 512 + sl * 64;
  short tmp[64];
#pragma unroll
  for (int k = 0; k < 16; ++k) {
    f32x4 f = *(const f32x4*)(src + k * 4);
    tmp[k*4+0] = f2bf(f[0]); tmp[k*4+1] = f2bf(f[1]);
    tmp[k*4+2] = f2bf(f[2]); tmp[k*4+3] = f2bf(f[3]);
  }
#pragma unroll
  for (int k = 0; k < 8; ++k) {
    short8 o8;
#pragma unroll
    for (int e = 0; e < 8; ++e) o8[e] = tmp[k * 8 + e];
    *(short8*)(out + ((o * 128 + k * 16) ^ ((o & 7) << 4))) = o8;
  }
}

// ---------------------------------------------------------------------------
// attn_db4: flash attention, S=4 split, double-buffered K/V in LDS +
// SWAPPED QK^T (S^T = mfma(K,Q)) with row-permuted K image: lane (g,i)
// ends holding P[i, 8g..8g+7] == the PV A-fragment; P never touches LDS.
// LDS 64KB, 256 thr, 2 blocks/CU (register-capped: ~230 regs/wave).
// Hot-loop pack uses __float2bfloat16 (HW cvt) — measured 7us faster than
// manual 3-op RNE (r9 vs r12 A/B).
// Writes bf16 partial O [s][b][c][i] and bf16 partial l [s][b][i] to ws.
// ---------------------------------------------------------------------------
__global__ __launch_bounds__(256, 2) void attn_db4(char* __restrict__ ws) {
  __shared__ __align__(16) char smem[65536];
  // buf0: K 0..16384, V 16384..32768 ; buf1: 32768..65536
  const int tid = threadIdx.x, lane = tid & 63, wv = tid >> 6;
  const int g = lane >> 4, l15 = lane & 15;
  const int p = blockIdx.x;
  const int L = (p & 7) * 64 + (p >> 3);
  const int b = L >> 7, s = (L >> 5) & 3, it = L & 31;
  const int i0 = it * 128;
  const int NT = 32;
  const char* qimg  = ws + WS_QT + (size_t)(b * 128 + it * 4) * 16384;
  const char* kbase = ws + WS_KT + (size_t)(b * 128 + s * NT) * 16384;
  const char* vbase = ws + WS_V  + (size_t)(b * 128 + s * NT) * 16384;

  // ---- stage the block's 4 Q tiles (64KB), pull wave's 32 rows to regs ----
#pragma unroll
  for (int k = 0; k < 16; ++k)
    gload16(qimg + k * 4096 + tid * 16, smem + k * 4096 + tid * 16);
  __syncthreads();
  short8 qf[2][8];
  {
    const char* qt = smem + wv * 16384;
#pragma unroll
    for (int qsub = 0; qsub < 2; ++qsub)
#pragma unroll
      for (int kb = 0; kb < 8; ++kb)
        qf[qsub][kb] = *(const short8*)(qt + (qsub * 16 + l15) * 512 +
                                        ((kb * 64 + g * 16) ^ ((l15 & 7) << 4)));
  }
  __syncthreads();

  f32x4 acc[2][16];
#pragma unroll
  for (int qsub = 0; qsub < 2; ++qsub)
#pragma unroll
    for (int nt = 0; nt < 16; ++nt) acc[qsub][nt] = (f32x4){0.f, 0.f, 0.f, 0.f};
  f32x4 accl[2];
  accl[0] = (f32x4){0.f, 0.f, 0.f, 0.f};
  accl[1] = (f32x4){0.f, 0.f, 0.f, 0.f};
  const float SL2E = 1.4426950408889634f / 16.0f;
  short8 ones;
#pragma unroll
  for (int e = 0; e < 8; ++e) ones[e] = (short)16256;  // bf16 1.0

  // prologue: stage tile 0 into buf0 (K 16KB + V 16KB)
#pragma unroll
  for (int k = 0; k < 4; ++k) {
    gload16(kbase + k * 4096 + tid * 16, smem + k * 4096 + tid * 16);
    gload16(vbase + k * 4096 + tid * 16, smem + 16384 + k * 4096 + tid * 16);
  }
  __syncthreads();

  int cur = 0;
  for (int t = 0; t < NT; ++t) {
    // prefetch t+1 into buf^1 BEFORE compute
    if (t + 1 < NT) {
      const char* ks = kbase + (size_t)(t + 1) * 16384;
      const char* vs = vbase + (size_t)(t + 1) * 16384;
      char* dst = smem + (cur ^ 1) * 32768 + tid * 16;
#pragma unroll
      for (int k = 0; k < 4; ++k) {
        gload16(ks + k * 4096 + tid * 16, dst + k * 4096);
        gload16(vs + k * 4096 + tid * 16, dst + 16384 + k * 4096);
      }
    }
    const char* bk = smem + cur * 32768;
    const char* bv = bk + 16384;
    // S^T = K Q^T (swapped): A = K image rows (permuted), B = Q.
    f32x4 s00 = (f32x4){0.f,0.f,0.f,0.f}, s01 = (f32x4){0.f,0.f,0.f,0.f};
    f32x4 s10 = (f32x4){0.f,0.f,0.f,0.f}, s11 = (f32x4){0.f,0.f,0.f,0.f};
    __builtin_amdgcn_s_setprio(1);
#pragma unroll
    for (int kb = 0; kb < 8; ++kb) {
      const int co = (kb * 64 + g * 16) ^ ((l15 & 7) << 4);
      short8 k0 = *(const short8*)(bk + l15 * 512 + co);
      short8 k1 = *(const short8*)(bk + (l15 + 16) * 512 + co);
      s00 = mfma16(k0, qf[0][kb], s00);
      s01 = mfma16(k1, qf[0][kb], s01);
      s10 = mfma16(k0, qf[1][kb], s10);
      s11 = mfma16(k1, qf[1][kb], s11);
    }
    __builtin_amdgcn_s_setprio(0);
    // P = exp2(s/16*log2e - 16), static max; pack IN REGISTERS (PV A-frag).
    short8 pf0, pf1;
#pragma unroll
    for (int r = 0; r < 4; ++r) {
      pf0[r]     = f2bf_rn(exp2f(fmaf(s00[r], SL2E, -16.0f)));
      pf0[4 + r] = f2bf_rn(exp2f(fmaf(s01[r], SL2E, -16.0f)));
      pf1[r]     = f2bf_rn(exp2f(fmaf(s10[r], SL2E, -16.0f)));
      pf1[4 + r] = f2bf_rn(exp2f(fmaf(s11[r], SL2E, -16.0f)));
    }
    __builtin_amdgcn_s_setprio(1);
    accl[0] = mfma16(pf0, ones, accl[0]);  // row-sums, free in accumulator
    accl[1] = mfma16(pf1, ones, accl[1]);
#pragma unroll
    for (int nt = 0; nt < 16; ++nt) {
      const int c = nt * 16 + l15;
      short8 vf = *(const short8*)(bv + ((c * 64 + g * 16) ^ ((c & 7) << 4)));
      acc[0][nt] = mfma16(pf0, vf, acc[0][nt]);
      acc[1][nt] = mfma16(pf1, vf, acc[1][nt]);
    }
    __builtin_amdgcn_s_setprio(0);
    __syncthreads();  // drains prefetch + protects buf swap
    cur ^= 1;
  }

  // epilogue: write bf16 partial O and l
  short* po = (short*)(ws + WS_PO) + (size_t)(s * NB + b) * CCH * HWX;
#pragma unroll
  for (int qsub = 0; qsub < 2; ++qsub)
#pragma unroll
    for (int nt = 0; nt < 16; ++nt) {
      const int c = nt * 16 + l15;
      short4v o4;
#pragma unroll
      for (int r = 0; r < 4; ++r) o4[r] = f2bf_rn(acc[qsub][nt][r]);
      *(short4v*)(po + (size_t)c * HWX + i0 + wv * 32 + qsub * 16 + g * 4) = o4;
    }
  if (l15 == 0) {
    short* pl = (short*)(ws + WS_PO + 4ull * 8388608ull) +
                (size_t)(s * NB + b) * HWX + i0 + wv * 32 + g * 4;
    short4v a4, b4;
#pragma unroll
    for (int r = 0; r < 4; ++r) { a4[r] = f2bf_rn(accl[0][r]); b4[r] = f2bf_rn(accl[1][r]); }
    *(short4v*)pl = a4;
    *(short4v*)(pl + 16) = b4;
  }
}

// ---------------------------------------------------------------------------
// attn_sb<S>: single-buffer fallback tiers (S=1,2), same swapped scheme.
// 128 thr / 2 waves, 64 q/block, LDS 32KB.
// ---------------------------------------------------------------------------
template <int S>
__global__ __launch_bounds__(128, 2) void attn_sb(char* __restrict__ ws) {
  __shared__ __align__(16) char smem[32768];
  const int tid = threadIdx.x, lane = tid & 63, wv = tid >> 6;
  const int g = lane >> 4, l15 = lane & 15;
  const int p = blockIdx.x;
  const int NT = 128 / S;
  int b, s, it;
  if (S == 2) {
    const int L = (p & 7) * 64 + (p >> 3);
    b = L >> 7; s = (L >> 6) & 1; it = L & 63;
  } else {
    const int L = (p & 7) * 32 + (p >> 3);
    b = L >> 6; s = 0; it = L & 63;
  }
  const int i0 = it * 64;
  const char* qimg  = ws + WS_QT + (size_t)(b * 128 + it * 2) * 16384;
  const char* kbase = ws + WS_KT + (size_t)(b * 128 + s * NT) * 16384;
  const char* vbase = ws + WS_V  + (size_t)(b * 128 + s * NT) * 16384;

#pragma unroll
  for (int k = 0; k < 16; ++k)
    gload16(qimg + k * 2048 + tid * 16, smem + k * 2048 + tid * 16);
  __syncthreads();
  short8 qf[2][8];
  {
    const char* qt = smem + wv * 16384;
#pragma unroll
    for (int qsub = 0; qsub < 2; ++qsub)
#pragma unroll
      for (int kb = 0; kb < 8; ++kb)
        qf[qsub][kb] = *(const short8*)(qt + (qsub * 16 + l15) * 512 +
                                        ((kb * 64 + g * 16) ^ ((l15 & 7) << 4)));
  }
  __syncthreads();

  f32x4 acc[2][16];
#pragma unroll
  for (int qsub = 0; qsub < 2; ++qsub)
#pragma unroll
    for (int nt = 0; nt < 16; ++nt) acc[qsub][nt] = (f32x4){0.f, 0.f, 0.f, 0.f};
  f32x4 accl[2];
  accl[0] = (f32x4){0.f, 0.f, 0.f, 0.f};
  accl[1] = (f32x4){0.f, 0.f, 0.f, 0.f};
  const float SL2E = 1.4426950408889634f / 16.0f;
  short8 ones;
#pragma unroll
  for (int e = 0; e < 8; ++e) ones[e] = (short)16256;

#pragma unroll
  for (int k = 0; k < 8; ++k) {
    gload16(kbase + k * 2048 + tid * 16, smem + k * 2048 + tid * 16);
    gload16(vbase + k * 2048 + tid * 16, smem + 16384 + k * 2048 + tid * 16);
  }
  __syncthreads();

  for (int t = 0; t < NT; ++t) {
    const char* bk = smem;
    const char* bv = smem + 16384;
    f32x4 s00 = (f32x4){0.f,0.f,0.f,0.f}, s01 = (f32x4){0.f,0.f,0.f,0.f};
    f32x4 s10 = (f32x4){0.f,0.f,0.f,0.f}, s11 = (f32x4){0.f,0.f,0.f,0.f};
    __builtin_amdgcn_s_setprio(1);
#pragma unroll
    for (int kb = 0; kb < 8; ++kb) {
      const int co = (kb * 64 + g * 16) ^ ((l15 & 7) << 4);
      short8 k0 = *(const short8*)(bk + l15 * 512 + co);
      short8 k1 = *(const short8*)(bk + (l15 + 16) * 512 + co);
      s00 = mfma16(k0, qf[0][kb], s00);
      s01 = mfma16(k1, qf[0][kb], s01);
      s10 = mfma16(k0, qf[1][kb], s10);
      s11 = mfma16(k1, qf[1][kb], s11);
    }
    __builtin_amdgcn_s_setprio(0);
    short8 pf0, pf1;
#pragma unroll
    for (int r = 0; r < 4; ++r) {
      pf0[r]     = f2bf_rn(exp2f(fmaf(s00[r], SL2E, -16.0f)));
      pf0[4 + r] = f2bf_rn(exp2f(fmaf(s01[r], SL2E, -16.0f)));
      pf1[r]     = f2bf_rn(exp2f(fmaf(s10[r], SL2E, -16.0f)));
      pf1[4 + r] = f2bf_rn(exp2f(fmaf(s11[r], SL2E, -16.0f)));
    }
    __builtin_amdgcn_s_setprio(1);
    accl[0] = mfma16(pf0, ones, accl[0]);
    accl[1] = mfma16(pf1, ones, accl[1]);
#pragma unroll
    for (int nt = 0; nt < 16; ++nt) {
      const int c = nt * 16 + l15;
      short8 vf = *(const short8*)(bv + ((c * 64 + g * 16) ^ ((c & 7) << 4)));
      acc[0][nt] = mfma16(pf0, vf, acc[0][nt]);
      acc[1][nt] = mfma16(pf1, vf, acc[1][nt]);
    }
    __builtin_amdgcn_s_setprio(0);
    __syncthreads();
    if (t + 1 < NT) {
      const char* ks = kbase + (size_t)(t + 1) * 16384;
      const char* vs = vbase + (size_t)(t + 1) * 16384;
#pragma unroll
      for (int k = 0; k < 8; ++k) {
        gload16(ks + k * 2048 + tid * 16, smem + k * 2048 + tid * 16);
        gload16(vs + k * 2048 + tid * 16, smem + 16384 + k * 2048 + tid * 16);
      }
    }
    __syncthreads();
  }

  short* po = (short*)(ws + WS_PO) + (size_t)(s * NB + b) * CCH * HWX;
#pragma unroll
  for (int qsub = 0; qsub < 2; ++qsub)
#pragma unroll
    for (int nt = 0; nt < 16; ++nt) {
      const int c = nt * 16 + l15;
      short4v o4;
#pragma unroll
      for (int r = 0; r < 4; ++r) o4[r] = f2bf_rn(acc[qsub][nt][r]);
      *(short4v*)(po + (size_t)c * HWX + i0 + wv * 32 + qsub * 16 + g * 4) = o4;
    }
  if (l15 == 0) {
    short* pl = (short*)(ws + WS_PO + (size_t)S * 8388608ull) +
                (size_t)(s * NB + b) * HWX + i0 + wv * 32 + g * 4;
    short4v a4, b4;
#pragma unroll
    for (int r = 0; r < 4; ++r) { a4[r] = f2bf_rn(accl[0][r]); b4[r] = f2bf_rn(accl[1][r]); }
    *(short4v*)pl = a4;
    *(short4v*)(pl + 16) = b4;
  }
}

// ---------------------------------------------------------------------------
// merge_feat<S>: sum bf16 partials, divide by summed l, write featT tile
// images (linear rows). grid = NB*128 (32-i tiles), 256 thr.
// ---------------------------------------------------------------------------
template <int S>
__global__ __launch_bounds__(256) void merge_feat(char* __restrict__ ws) {
  __shared__ float linv[32];
  __shared__ short ldsT[32 * 66];
  const int tid = threadIdx.x;
  const int p = blockIdx.x;
  const int L = (p & 7) * 64 + (p >> 3);
  const int b = L >> 7, it = L & 127, i0 = it * 32;
  const short* po = (const short*)(ws + WS_PO);
  const short* pl = (const short*)(ws + WS_PO + (size_t)S * 8388608ull);
  if (tid < 32) {
    float l = 0.0f;
#pragma unroll
    for (int s = 0; s < S; ++s)
      l += bf2f(pl[(size_t)(s * NB + b) * HWX + i0 + tid]);
    linv[tid] = 1.0f / l;
  }
  __syncthreads();
  char* fout = ws + WS_FT + (size_t)(b * 128 + it) * 16384;
#pragma unroll
  for (int ch = 0; ch < 4; ++ch) {
    const int c = ch * 64 + (tid >> 2);
    const int qo = (tid & 3) * 8;
    float a[8];
#pragma unroll
    for (int e = 0; e < 8; ++e) a[e] = 0.0f;
#pragma unroll
    for (int s = 0; s < S; ++s) {
      short8 v8 = *(const short8*)(po + (size_t)(s * NB + b) * CCH * HWX +
                                   (size_t)c * HWX + i0 + qo);
#pragma unroll
      for (int e = 0; e < 8; ++e) a[e] += bf2f(v8[e]);
    }
#pragma unroll
    for (int e = 0; e < 8; ++e)
      ldsT[(qo + e) * 66 + (tid >> 2)] = f2bf(a[e] * linv[qo + e]);
    __syncthreads();
    {
      const int i = tid >> 3, m = tid & 7;
      short8 o8;
#pragma unroll
      for (int e = 0; e < 8; ++e) o8[e] = ldsT[i * 66 + m * 8 + e];
      *(short8*)(fout + ((i * 512 + ch * 128 + m * 16) ^ ((i & 7) << 4))) = o8;
    }
    __syncthreads();
  }
}

// ---------------------------------------------------------------------------
// conv_mfma: y = PReLU(BN(W * [featT; curT] + b)).  grid = NB*128 (32-i tiles).
// Slices 0-3 read ft (linear rows); slices 4-7 read kt (PERMUTED rows) ->
// bx row index goes through kt_invmap (2-way LDS conflict = free).
// ---------------------------------------------------------------------------
__global__ __launch_bounds__(256) void conv_mfma(const float* __restrict__ bconv,
                                                 const float* __restrict__ gamma,
                                                 const float* __restrict__ beta,
                                                 const float* __restrict__ rmean,
                                                 const float* __restrict__ rvar,
                                                 const float* __restrict__ alpha,
                                                 char* __restrict__ ws,
                                                 float* __restrict__ out) {
  __shared__ __align__(16) char smem[73728];
  const int tid = threadIdx.x, lane = tid & 63, wv = tid >> 6;
  const int g = lane >> 4, l15 = lane & 15;
  const int p = blockIdx.x;
  const int L = (p & 7) * 64 + (p >> 3);
  const int b = L >> 7, it = L & 127, i0 = it * 32;
  const char* wimg = ws + WS_W;
  const char* ft = ws + WS_FT + (size_t)(b * 128 + it) * 16384;
  const char* kt = ws + WS_KT + (size_t)(b * 128 + it) * 16384;

  f32x4 acc[4][2];
#pragma unroll
  for (int ot = 0; ot < 4; ++ot)
#pragma unroll
    for (int itt = 0; itt < 2; ++itt) acc[ot][itt] = (f32x4){0.f, 0.f, 0.f, 0.f};

  const int xi = wv * 8 + (lane >> 3), xw = (lane & 7) * 16;

#pragma unroll
  for (int k = 0; k < 8; ++k)
    gload16(wimg + wv * 8192 + k * 1024 + lane * 16,
            smem + wv * 8192 + k * 1024 + lane * 16);
  gload16(ft + xi * 512 + xw, smem + 65536 + wv * 1024 + lane * 16);
  __syncthreads();

  int cur = 0;
  for (int st = 0; st < 8; ++st) {
    if (st < 7) {
      const int sn = st + 1;
      const char* img = (sn < 4) ? ft : kt;
      const int coff = (sn & 3) * 128;
#pragma unroll
      for (int k = 0; k < 8; ++k)
        gload16(wimg + (size_t)sn * 32768 + wv * 8192 + k * 1024 + lane * 16,
                smem + (cur ^ 1) * 32768 + wv * 8192 + k * 1024 + lane * 16);
      gload16(img + xi * 512 + coff + xw,
              smem + 65536 + (cur ^ 1) * 4096 + wv * 1024 + lane * 16);
    }
    const char* wb = smem + cur * 32768;
    const char* xb = smem + 65536 + cur * 4096;
    short8 bx[2][2];
#pragma unroll
    for (int itt = 0; itt < 2; ++itt) {
      const int i = itt * 16 + l15;
      const int ii = (st < 4) ? i : kt_invmap(i);
#pragma unroll
      for (int kb = 0; kb < 2; ++kb)
        bx[itt][kb] = *(const short8*)(xb + ii * 128 + ((kb * 64 + g * 16) ^ ((ii & 7) << 4)));
    }
#pragma unroll
    for (int ot = 0; ot < 4; ++ot) {
      const int o = wv * 64 + ot * 16 + l15;
#pragma unroll
      for (int kb = 0; kb < 2; ++kb) {
        short8 aw = *(const short8*)(wb + o * 128 + ((kb * 64 + g * 16) ^ ((o & 7) << 4)));
#pragma unroll
        for (int itt = 0; itt < 2; ++itt)
          acc[ot][itt] = mfma16(aw, bx[itt][kb], acc[ot][itt]);
      }
    }
    __syncthreads();
    cur ^= 1;
  }

  const float a0 = alpha[0];
  float* outB = out + (size_t)b * CCH * HWX;
#pragma unroll
  for (int ot = 0; ot < 4; ++ot)
#pragma unroll
    for (int r = 0; r < 4; ++r) {
      const int o = wv * 64 + ot * 16 + g * 4 + r;
      const float inv = gamma[o] * rsqrtf(rvar[o] + 1e-5f);
      const float add = beta[o] - rmean[o] * inv + bconv[o] * inv;
#pragma unroll
      for (int itt = 0; itt < 2; ++itt) {
        float v = acc[ot][itt][r] * inv + add;
        v = (v >= 0.0f) ? v : a0 * v;
        outB[(size_t)o * HWX + i0 + itt * 16 + l15] = v;
      }
    }
}

// ===========================================================================
// Legacy fallback (round-2, validated) for small ws_size
// ===========================================================================
__global__ __launch_bounds__(256) void legacy_attn(const float* __restrict__ pre,
                                                   const float* __restrict__ cur,
                                                   float* __restrict__ feat) {
  __shared__ __align__(16) char smem[43008];
  short* lds_q  = (short*)smem;
  short* lds_kT = (short*)smem;
  short* lds_v  = (short*)(smem + 16896);
  short* lds_p  = (short*)(smem + 37376);
  const int tid = threadIdx.x, lane = tid & 63, wv = tid >> 6;
  const int b = blockIdx.x >> 6, i0 = (blockIdx.x & 63) * 64;
  const float* preB = pre + (size_t)b * CCH * HWX;
  const float* curB = cur + (size_t)b * CCH * HWX;
  float* featB = feat + (size_t)b * CCH * HWX;
  {
    const int ib = (tid & 15) * 4, cbb = (tid >> 4) * 4;
#pragma unroll
    for (int p = 0; p < 4; ++p) {
      const int c = cbb + 64 * p;
      f32x4 f[4];
#pragma unroll
      for (int r = 0; r < 4; ++r)
        f[r] = *(const f32x4*)(preB + (size_t)(c + r) * HWX + i0 + ib);
#pragma unroll
      for (int e = 0; e < 4; ++e) {
        short4v s2;
        s2[0] = f2bf(f[0][e]); s2[1] = f2bf(f[1][e]);
        s2[2] = f2bf(f[2][e]); s2[3] = f2bf(f[3][e]);
        *(short4v*)(&lds_q[(ib + e) * 264 + c]) = s2;
      }
    }
  }
  __syncthreads();
  short8 qf[8];
  {
    const int r = wv * 16 + (lane & 15), ko = (lane >> 4) * 8;
#pragma unroll
    for (int kb = 0; kb < 8; ++kb)
      qf[kb] = *(const short8*)(&lds_q[r * 264 + kb * 32 + ko]);
  }
  f32x4 acc[16];
#pragma unroll
  for (int nt = 0; nt < 16; ++nt) acc[nt] = (f32x4){0.f, 0.f, 0.f, 0.f};
  float m_run[4], l_run[4];
#pragma unroll
  for (int r = 0; r < 4; ++r) { m_run[r] = -1e30f; l_run[r] = 0.0f; }
  const float SL2E = 1.4426950408889634f / 16.0f;
  for (int jt = 0; jt < 128; ++jt) {
    const int j0 = jt * 32;
    __syncthreads();
    {
      const int jb = (tid & 7) * 4, cbb = (tid >> 3) * 4;
#pragma unroll
      for (int p = 0; p < 2; ++p) {
        const int c = cbb + 128 * p;
        f32x4 f[4];
#pragma unroll
        for (int r = 0; r < 4; ++r)
          f[r] = *(const f32x4*)(curB + (size_t)(c + r) * HWX + j0 + jb);
#pragma unroll
        for (int r = 0; r < 4; ++r) {
          short4v s2;
          s2[0] = f2bf(f[r][0]); s2[1] = f2bf(f[r][1]);
          s2[2] = f2bf(f[r][2]); s2[3] = f2bf(f[r][3]);
          *(short4v*)(&lds_v[(c + r) * 40 + jb]) = s2;
        }
#pragma unroll
        for (int e = 0; e < 4; ++e) {
          short4v s2;
          s2[0] = f2bf(f[0][e]); s2[1] = f2bf(f[1][e]);
          s2[2] = f2bf(f[2][e]); s2[3] = f2bf(f[3][e]);
          *(short4v*)(&lds_kT[(jb + e) * 264 + c]) = s2;
        }
      }
    }
    __syncthreads();
    f32x4 s0 = (f32x4){0.f,0.f,0.f,0.f}, s1 = (f32x4){0.f,0.f,0.f,0.f};
    {
      const int jc = lane & 15, ko = (lane >> 4) * 8;
#pragma unroll
      for (int kb = 0; kb < 8; ++kb) {
        short8 k0 = *(const short8*)(&lds_kT[jc * 264 + kb * 32 + ko]);
        short8 k1 = *(const short8*)(&lds_kT[(jc + 16) * 264 + kb * 32 + ko]);
        s0 = mfma16(qf[kb], k0, s0);
        s1 = mfma16(qf[kb], k1, s1);
      }
    }
    float p0[4], p1[4], corr[4];
#pragma unroll
    for (int r = 0; r < 4; ++r) {
      float t = fmaxf(s0[r], s1[r]);
      t = fmaxf(t, __shfl_xor(t, 1)); t = fmaxf(t, __shfl_xor(t, 2));
      t = fmaxf(t, __shfl_xor(t, 4)); t = fmaxf(t, __shfl_xor(t, 8));
      const float mn = fmaxf(m_run[r], t * SL2E);
      corr[r] = exp2f(m_run[r] - mn);
      m_run[r] = mn;
      p0[r] = exp2f(s0[r] * SL2E - mn);
      p1[r] = exp2f(s1[r] * SL2E - mn);
      float rs = p0[r] + p1[r];
      rs += __shfl_xor(rs, 1); rs += __shfl_xor(rs, 2);
      rs += __shfl_xor(rs, 4); rs += __shfl_xor(rs, 8);
      l_run[r] = l_run[r] * corr[r] + rs;
    }
#pragma unroll
    for (int nt = 0; nt < 16; ++nt)
#pragma unroll
      for (int r = 0; r < 4; ++r) acc[nt][r] *= corr[r];
    {
      short* pw = lds_p + wv * 640;
      const int g2 = lane >> 4, jc = lane & 15;
#pragma unroll
      for (int r = 0; r < 4; ++r) {
        pw[(g2 * 4 + r) * 40 + jc]      = f2bf(p0[r]);
        pw[(g2 * 4 + r) * 40 + 16 + jc] = f2bf(p1[r]);
      }
    }
    {
      const int g2 = lane >> 4, rr = lane & 15;
      short8 pf = *(const short8*)(&lds_p[wv * 640 + rr * 40 + g2 * 8]);
#pragma unroll
      for (int nt = 0; nt < 16; ++nt) {
        short8 vf = *(const short8*)(&lds_v[(nt * 16 + rr) * 40 + g2 * 8]);
        acc[nt] = mfma16(pf, vf, acc[nt]);
      }
    }
  }
  {
    const int g2 = lane >> 4, jc = lane & 15;
    float rl[4];
#pragma unroll
    for (int r = 0; r < 4; ++r) rl[r] = 1.0f / l_run[r];
#pragma unroll
    for (int nt = 0; nt < 16; ++nt) {
      const int c = nt * 16 + jc;
#pragma unroll
      for (int r = 0; r < 4; ++r)
        featB[(size_t)c * HWX + i0 + wv * 16 + g2 * 4 + r] = acc[nt][r] * rl[r];
    }
  }
}

__global__ __launch_bounds__(256) void legacy_conv(const float* feat,
                                                   const float* __restrict__ cur,
                                                   const float* __restrict__ Wm,
                                                   const float* __restrict__ bconv,
                                                   const float* __restrict__ gamma,
                                                   const float* __restrict__ beta,
                                                   const float* __restrict__ rmean,
                                                   const float* __restrict__ rvar,
                                                   const float* __restrict__ alpha,
                                                   float* out) {
  __shared__ __align__(16) char smem[25600];
  short* lds_w = (short*)smem;
  short* lds_x = (short*)(smem + 20480);
  const int tid = threadIdx.x, lane = tid & 63, wv = tid >> 6;
  const int b = blockIdx.x >> 6, i0 = (blockIdx.x & 63) * 64;
  const float* featB = feat + (size_t)b * CCH * HWX;
  const float* curB  = cur  + (size_t)b * CCH * HWX;
  f32x4 acc[4][4];
#pragma unroll
  for (int ot = 0; ot < 4; ++ot)
#pragma unroll
    for (int it = 0; it < 4; ++it) acc[ot][it] = (f32x4){0.f, 0.f, 0.f, 0.f};
  for (int ks = 0; ks < 16; ++ks) {
    const int k0 = ks * 32;
    __syncthreads();
    {
      const int kq = (tid & 7) * 4, ob = tid >> 3;
#pragma unroll
      for (int p = 0; p < 8; ++p) {
        const int o = ob + 32 * p;
        f32x4 f = *(const f32x4*)(Wm + (size_t)o * 512 + k0 + kq);
        short4v s2;
        s2[0] = f2bf(f[0]); s2[1] = f2bf(f[1]); s2[2] = f2bf(f[2]); s2[3] = f2bf(f[3]);
        *(short4v*)(&lds_w[o * 40 + kq]) = s2;
      }
    }
    {
      const int i2 = (tid & 31) * 2, cc = ((tid >> 5) & 7) * 4;
      const float* basep = (k0 < 256) ? (featB + (size_t)(k0 + cc) * HWX)
                                      : (curB + (size_t)(k0 + cc - 256) * HWX);
      f32x2 f[4];
#pragma unroll
      for (int r = 0; r < 4; ++r)
        f[r] = *(const f32x2*)(basep + (size_t)r * HWX + i0 + i2);
#pragma unroll
      for (int e = 0; e < 2; ++e) {
        short4v s2;
        s2[0] = f2bf(f[0][e]); s2[1] = f2bf(f[1][e]);
        s2[2] = f2bf(f[2][e]); s2[3] = f2bf(f[3][e]);
        *(short4v*)(&lds_x[(i2 + e) * 40 + cc]) = s2;
      }
    }
    __syncthreads();
    {
      const int g = lane >> 4, rr = lane & 15;
      short8 af[4], bx[4];
#pragma unroll
      for (int ot = 0; ot < 4; ++ot)
        af[ot] = *(const short8*)(&lds_w[(wv * 64 + ot * 16 + rr) * 40 + g * 8]);
#pragma unroll
      for (int it = 0; it < 4; ++it)
        bx[it] = *(const short8*)(&lds_x[(it * 16 + rr) * 40 + g * 8]);
#pragma unroll
      for (int ot = 0; ot < 4; ++ot)
#pragma unroll
        for (int it = 0; it < 4; ++it)
          acc[ot][it] = mfma16(af[ot], bx[it], acc[ot][it]);
    }
  }
  const float a0 = alpha[0];
  const int g = lane >> 4, ic = lane & 15;
  float* outB = out + (size_t)b * CCH * HWX;
#pragma unroll
  for (int ot = 0; ot < 4; ++ot)
#pragma unroll
    for (int r = 0; r < 4; ++r) {
      const int o = wv * 64 + ot * 16 + g * 4 + r;
      const float inv = gamma[o] * rsqrtf(rvar[o] + 1e-5f);
      const float add = beta[o] - rmean[o] * inv + bconv[o] * inv;
#pragma unroll
      for (int it = 0; it < 4; ++it) {
        float v = acc[ot][it][r] * inv + add;
        v = (v >= 0.0f) ? v : a0 * v;
        outB[(size_t)o * HWX + i0 + it * 16 + ic] = v;
      }
    }
}

extern "C" void kernel_launch(void* const* d_in, const int* in_sizes, int n_in,
                              void* d_out, int out_size, void* d_ws, size_t ws_size,
                              hipStream_t stream) {
  (void)in_sizes; (void)n_in; (void)out_size;
  const float* pre   = (const float*)d_in[0];
  const float* cur   = (const float*)d_in[1];
  const float* Wm    = (const float*)d_in[2];
  const float* bconv = (const float*)d_in[3];
  const float* gamma = (const float*)d_in[4];
  const float* beta  = (const float*)d_in[5];
  const float* rmean = (const float*)d_in[6];
  const float* rvar  = (const float*)d_in[7];
  const float* alpha = (const float*)d_in[8];
  float* out = (float*)d_out;
  char* ws = (char*)d_ws;

  const size_t need4 = WS_PO + 4ull * (8388608ull + 32768ull);  // 67,502,080
  const size_t need2 = WS_PO + 2ull * (8388608ull + 32768ull);
  const size_t need1 = WS_PO + 1ull * (8388608ull + 32768ull);

  if (ws_size >= need1) {
    prep_qkv<<<dim3(512), dim3(256), 0, stream>>>(pre, cur, ws);
    prep_w<<<dim3(8), dim3(256), 0, stream>>>(Wm, ws);
    if (ws_size >= need4) {
      attn_db4<<<dim3(512), dim3(256), 0, stream>>>(ws);
      merge_feat<4><<<dim3(512), dim3(256), 0, stream>>>(ws);
    } else if (ws_size >= need2) {
      attn_sb<2><<<dim3(512), dim3(128), 0, stream>>>(ws);
      merge_feat<2><<<dim3(512), dim3(256), 0, stream>>>(ws);
    } else {
      attn_sb<1><<<dim3(256), dim3(128), 0, stream>>>(ws);
      merge_feat<1><<<dim3(512), dim3(256), 0, stream>>>(ws);
    }
    conv_mfma<<<dim3(512), dim3(256), 0, stream>>>(bconv, gamma, beta, rmean,
                                                   rvar, alpha, ws, out);
  } else {
    legacy_attn<<<dim3(256), dim3(256), 0, stream>>>(pre, cur, out);
    legacy_conv<<<dim3(256), dim3(256), 0, stream>>>(out, cur, Wm, bconv, gamma,
                                                     beta, rmean, rvar, alpha, out);
  }
}